// Round 1
// 359.080 us; speedup vs baseline: 1.1195x; 1.1195x over previous
//
#include <hip/hip_runtime.h>

// SubjBasisGenerator fused pipeline. B=4 NQ=416 NC=257 D=768 H=6 DH=128 G=104 R=4 LORA=64
// R11: (1) O-gemm + combine fused into oc_k — combine only consumes the
//      head-diagonal 128-col slice of each O row, so the batched 24x768 GEMM
//      did 6x wasted FLOPs + 30MB Obf traffic. oc_k computes exactly the
//      needed 24x128-per-head slices on the VALU (0.16 GF).
//      (2) Wconv pre-converted to bf16 (WcvB) -> Gram gemm takes the fast
//      u32x4 staging path (same f2bf rounding, identical numerics).
//      (3) Y-gemm/stats2 de-chunked (full 13.7MB Y buffer), conv/transpose
//      prep fused (convb3/transb3). ~30 -> 23 dispatches.
// R10: big row-major GEMMs (q/k/mid/final) on gemm128 — 128x128 tile,
//      4x4 MFMA acc/wave, global_load_lds width-16 async staging.
//
// Algebra: the grouped-conv+LN v-path decomposes exactly (no (B,G,NC,768) tensor):
//   sum_j A_j v_j = gv2*( (sum_j A_j inv_j mid_j)@Wconv[g] - sum_j A_j inv_j mu_j )
//                   + bv2 + (A @ ctx)
//   q2[b,g,j] = mid^T M[g] mid = mid . (M[g] @ mid),  M[g] = Wconv[g]Wconv[g]^T/768

typedef unsigned short u16;
typedef unsigned int   u32;
typedef __attribute__((ext_vector_type(4))) float f32x4;
typedef __attribute__((ext_vector_type(4))) u32   u32x4;
typedef __attribute__((ext_vector_type(8))) short bf16x8;

__device__ __forceinline__ float bf2f(u16 v) { return __uint_as_float(((u32)v) << 16); }
__device__ __forceinline__ u16 f2bf(float f) {
  u32 u = __float_as_uint(f);
  u32 r = u + 0x7fffu + ((u >> 16) & 1u);  // RNE
  return (u16)(r >> 16);
}
__device__ __forceinline__ float gld(const void* p, long idx, int f32) {
  return f32 ? ((const float*)p)[idx] : bf2f(((const u16*)p)[idx]);
}

typedef const __attribute__((address_space(1))) u32 gas_u32;
typedef __attribute__((address_space(3))) u32 las_u32;

// async 16B/lane global->LDS; LDS dest = wave-uniform base + lane*16 (m97).
__device__ __forceinline__ void stage16(const u16* g, u16* lbase, int lane) {
#if __has_builtin(__builtin_amdgcn_global_load_lds)
  (void)lane;
  __builtin_amdgcn_global_load_lds((gas_u32*)g, (las_u32*)lbase, 16, 0, 0);
#else
  *(u32x4*)(lbase + lane * 8) = *(const u32x4*)g;
#endif
}

// ------------------------------------------------------------ dtype probe ---
__global__ __launch_bounds__(256) void probe_k(const u32* __restrict__ xw, int* __restrict__ flag) {
  int tid = threadIdx.x, c = 0;
  for (int i = tid; i < 4096; i += 256) {
    u16 lo = (u16)(xw[i] & 0xffffu);
    float a = fabsf(bf2f(lo));
    if (lo == 0 || (a >= 1e-3f && a <= 32.f)) ++c;
  }
#pragma unroll
  for (int o = 32; o; o >>= 1) c += __shfl_xor(c, o, 64);
  __shared__ int r[4];
  if ((tid & 63) == 0) r[tid >> 6] = c;
  __syncthreads();
  if (tid == 0) flag[0] = (r[0] + r[1] + r[2] + r[3] >= 2048) ? 0 : 1;  // 1 = fp32
}

// ------------------------------------------------------------ diag fill -----
__global__ __launch_bounds__(256) void fill_k(u16* p, float v, int n) {
  int i = blockIdx.x * 256 + threadIdx.x;
  if (i < n) p[i] = f2bf(v);
}

// ------------------------------------- ext -> bf16 copy, 3 tensors fused ----
__global__ __launch_bounds__(256) void convb3_k(
    const void* __restrict__ s0, u16* __restrict__ d0, int n0_,
    const void* __restrict__ s1, u16* __restrict__ d1, int n1_,
    const void* __restrict__ s2, u16* __restrict__ d2, int n2_,
    const int* __restrict__ dtf)
{
  const int f = dtf[0];
  long i = ((long)blockIdx.x * 256 + threadIdx.x) * 8;
  const void* in; u16* out;
  if (i < n0_)                  { in = s0; out = d0; }
  else if (i < (long)n0_ + n1_) { in = s1; out = d1; i -= n0_; }
  else if (i < (long)n0_ + n1_ + n2_) { in = s2; out = d2; i -= (long)n0_ + n1_; }
  else return;
  if (f) {
    const float* ip = (const float*)in + i;
    f32x4 a = *(const f32x4*)ip, b = *(const f32x4*)(ip + 4);
    u32x4 q = { (u32)f2bf(a.x) | ((u32)f2bf(a.y) << 16),
                (u32)f2bf(a.z) | ((u32)f2bf(a.w) << 16),
                (u32)f2bf(b.x) | ((u32)f2bf(b.y) << 16),
                (u32)f2bf(b.z) | ((u32)f2bf(b.w) << 16) };
    *(u32x4*)(out + i) = q;
  } else {
    *(u32x4*)(out + i) = *(const u32x4*)((const u16*)in + i);
  }
}

// ------------------------------------- ext [K,N] -> bf16 [N,K] transpose ----
__global__ __launch_bounds__(256) void transb_k(const void* __restrict__ in, u16* __restrict__ out,
                                                int K, int N, const int* __restrict__ dtf) {
  const int f = dtf[0];
  __shared__ float s[32][33];
  int n0 = blockIdx.x * 32, k0 = blockIdx.y * 32;
  int tx = threadIdx.x & 31, ty = threadIdx.x >> 5;  // 32 x 8
#pragma unroll
  for (int i = 0; i < 32; i += 8) {
    int k = k0 + ty + i, n = n0 + tx;
    float v = 0.f;
    if (k < K && n < N) v = gld(in, (long)k * N + n, f);
    s[ty + i][tx] = v;
  }
  __syncthreads();
#pragma unroll
  for (int i = 0; i < 32; i += 8) {
    int n = n0 + ty + i, k = k0 + tx;
    if (n < N && k < K) out[(long)n * K + k] = f2bf(s[tx][ty + i]);
  }
}

// three 768x768 transposes in one launch (Wq, Wk, Wo)
__global__ __launch_bounds__(256) void transb3_k(
    const void* __restrict__ s0_, const void* __restrict__ s1_, const void* __restrict__ s2_,
    u16* __restrict__ d0_, u16* __restrict__ d1_, u16* __restrict__ d2_,
    const int* __restrict__ dtf)
{
  const int f = dtf[0];
  const void* in = blockIdx.z == 0 ? s0_ : blockIdx.z == 1 ? s1_ : s2_;
  u16* out       = blockIdx.z == 0 ? d0_ : blockIdx.z == 1 ? d1_ : d2_;
  __shared__ float s[32][33];
  int n0 = blockIdx.x * 32, k0 = blockIdx.y * 32;
  int tx = threadIdx.x & 31, ty = threadIdx.x >> 5;
#pragma unroll
  for (int i = 0; i < 32; i += 8)
    s[ty + i][tx] = gld(in, (long)(k0 + ty + i) * 768 + n0 + tx, f);
  __syncthreads();
#pragma unroll
  for (int i = 0; i < 32; i += 8)
    out[(long)(n0 + ty + i) * 768 + k0 + tx] = f2bf(s[tx][ty + i]);
}

// ------------------------------------------------------------- gemm128 ------
// C_bf16 = A_bf16[M,K] @ B_bf16[N,K]^T. Requires N%128==0, K%32==0; M-tail via
// row-clamped staging + guarded writes. 128x128 tile, BK=32, 4 waves each 64x64
// (4x4 mfma_f32_16x16x32_bf16). LDS unpadded [row][32] fed by stage16.
__global__ __launch_bounds__(256) void gemm128(
    const u16* __restrict__ A, const u16* __restrict__ B, u16* __restrict__ C,
    int M, int N, int K, int lda, int ldb, int ldc)
{
  __shared__ __attribute__((aligned(16))) u16 As[128 * 32];
  __shared__ __attribute__((aligned(16))) u16 Bs[128 * 32];
  const int tid = threadIdx.x, lane = tid & 63, wave = tid >> 6;
  const int m0 = blockIdx.x * 128, n0 = blockIdx.y * 128;
  const int wm = (wave >> 1) * 64, wn = (wave & 1) * 64;
  const int fm = lane & 15, fq = lane >> 4;

  const int srow = lane >> 2, selem = (lane & 3) * 8;
  int ra1 = m0 + wave * 16 + srow;      if (ra1 > M - 1) ra1 = M - 1;
  int ra2 = m0 + 64 + wave * 16 + srow; if (ra2 > M - 1) ra2 = M - 1;
  const int rb1 = n0 + wave * 16 + srow;
  const int rb2 = n0 + 64 + wave * 16 + srow;
  const u16* pa1 = A + (long)ra1 * lda + selem;
  const u16* pa2 = A + (long)ra2 * lda + selem;
  const u16* pb1 = B + (long)rb1 * ldb + selem;
  const u16* pb2 = B + (long)rb2 * ldb + selem;
  u16* la1 = As + wave * 512;
  u16* la2 = As + 2048 + wave * 512;
  u16* lb1 = Bs + wave * 512;
  u16* lb2 = Bs + 2048 + wave * 512;

  f32x4 acc[4][4];
  const f32x4 zero4 = {0.f, 0.f, 0.f, 0.f};
#pragma unroll
  for (int a_ = 0; a_ < 4; ++a_)
#pragma unroll
    for (int b_ = 0; b_ < 4; ++b_) acc[a_][b_] = zero4;

  for (int k0 = 0; k0 < K; k0 += 32) {
    stage16(pa1, la1, lane);
    stage16(pa2, la2, lane);
    stage16(pb1, lb1, lane);
    stage16(pb2, lb2, lane);
    pa1 += 32; pa2 += 32; pb1 += 32; pb2 += 32;
    __syncthreads();
    bf16x8 fa[4], fb[4];
#pragma unroll
    for (int mt = 0; mt < 4; ++mt)
      fa[mt] = *(const bf16x8*)&As[(wm + mt * 16 + fm) * 32 + fq * 8];
#pragma unroll
    for (int nt = 0; nt < 4; ++nt)
      fb[nt] = *(const bf16x8*)&Bs[(wn + nt * 16 + fm) * 32 + fq * 8];
#pragma unroll
    for (int mt = 0; mt < 4; ++mt)
#pragma unroll
      for (int nt = 0; nt < 4; ++nt)
        acc[mt][nt] = __builtin_amdgcn_mfma_f32_16x16x32_bf16(fa[mt], fb[nt], acc[mt][nt], 0, 0, 0);
    __syncthreads();
  }
#pragma unroll
  for (int mt = 0; mt < 4; ++mt)
#pragma unroll
    for (int nt = 0; nt < 4; ++nt)
#pragma unroll
      for (int rr = 0; rr < 4; ++rr) {
        int gm = m0 + wm + mt * 16 + fq * 4 + rr;
        int gn = n0 + wn + nt * 16 + fm;
        if (gm < M) C[(long)gm * ldc + gn] = f2bf(acc[mt][nt][rr]);
      }
}

// ---------------------------------------------------------------- GEMM ------
// (64x64 general kernel — batched / flag-dtype / fp32-out cases)
#define LDS_S 40

__global__ __launch_bounds__(256) void gemm_bf16(
    const void* __restrict__ A, const void* __restrict__ B,
    float* __restrict__ Cf, u16* __restrict__ Cb, int obf,
    int M, int N, int K, int lda, int ldb, int ldc,
    long sAo, long sAi, int adiv, long sBo, long sBi, int bdiv,
    long sC, int zoff, int btrans, float alpha,
    const int* __restrict__ dtf, int aSel, int bSel)
{
  const int f = dtf[0];
  const int af32 = aSel & f, bf32 = bSel & f;
  const int zl = blockIdx.z, zg = zl + zoff;
  const long aoff = (long)(zg / adiv) * sAo + (long)(zg % adiv) * sAi;
  const long boff = (long)(zg / bdiv) * sBo + (long)(zg % bdiv) * sBi;
  const u16*   A16 = (const u16*)A + aoff;
  const float* A32 = (const float*)A + aoff;
  const u16*   B16 = (const u16*)B + boff;
  const float* B32 = (const float*)B + boff;

  __shared__ __attribute__((aligned(16))) u16 As[64 * LDS_S];
  __shared__ __attribute__((aligned(16))) u16 Bs[64 * LDS_S];

  const int tid = threadIdx.x;
  const int lane = tid & 63, wave = tid >> 6;
  const int m0 = blockIdx.x * 64, n0 = blockIdx.y * 64;
  const int wm = (wave >> 1) * 32, wn = (wave & 1) * 32;
  const int fm = lane & 15, fq = lane >> 4;

  const int ar = tid >> 2, ak = (tid & 3) * 8;
  const int bk = tid >> 3, bn = (tid & 7) * 8;

  f32x4 acc[2][2];
  const f32x4 zero4 = {0.f, 0.f, 0.f, 0.f};
#pragma unroll
  for (int a_ = 0; a_ < 2; ++a_)
#pragma unroll
    for (int b_ = 0; b_ < 2; ++b_) acc[a_][b_] = zero4;

  for (int k0 = 0; k0 < K; k0 += 32) {
    {
      int gm = m0 + ar, gk = k0 + ak;
      long idx = (long)gm * lda + gk;
      if (gm < M && gk + 8 <= K) {
        if (af32) {
          f32x4 u = *(const f32x4*)(A32 + idx), v = *(const f32x4*)(A32 + idx + 4);
          u32x4 q = { (u32)f2bf(u.x) | ((u32)f2bf(u.y) << 16),
                      (u32)f2bf(u.z) | ((u32)f2bf(u.w) << 16),
                      (u32)f2bf(v.x) | ((u32)f2bf(v.y) << 16),
                      (u32)f2bf(v.z) | ((u32)f2bf(v.w) << 16) };
          *(u32x4*)&As[ar * LDS_S + ak] = q;
        } else {
          *(u32x4*)&As[ar * LDS_S + ak] = *(const u32x4*)(A16 + idx);
        }
      } else {
#pragma unroll
        for (int e = 0; e < 8; ++e) {
          u16 v = 0;
          if (gm < M && gk + e < K) v = f2bf(gld(A, aoff + idx + e, af32));
          As[ar * LDS_S + ak + e] = v;
        }
      }
    }
    if (btrans) {
      int gn = n0 + ar, gk = k0 + ak;
      long idx = (long)gn * ldb + gk;
      if (gn < N && gk + 8 <= K) {
        if (bf32) {
          f32x4 u = *(const f32x4*)(B32 + idx), v = *(const f32x4*)(B32 + idx + 4);
          u32x4 q = { (u32)f2bf(u.x) | ((u32)f2bf(u.y) << 16),
                      (u32)f2bf(u.z) | ((u32)f2bf(u.w) << 16),
                      (u32)f2bf(v.x) | ((u32)f2bf(v.y) << 16),
                      (u32)f2bf(v.z) | ((u32)f2bf(v.w) << 16) };
          *(u32x4*)&Bs[ar * LDS_S + ak] = q;
        } else {
          *(u32x4*)&Bs[ar * LDS_S + ak] = *(const u32x4*)(B16 + idx);
        }
      } else {
#pragma unroll
        for (int e = 0; e < 8; ++e) {
          u16 v = 0;
          if (gn < N && gk + e < K) v = f2bf(gld(B, boff + idx + e, bf32));
          Bs[ar * LDS_S + ak + e] = v;
        }
      }
    } else {
      int gk = k0 + bk;
      long idx = (long)gk * ldb + n0 + bn;
      u16 tmp[8];
      if (gk < K) {
        if (bf32) {
          f32x4 u = *(const f32x4*)(B32 + idx), v = *(const f32x4*)(B32 + idx + 4);
          tmp[0] = f2bf(u.x); tmp[1] = f2bf(u.y); tmp[2] = f2bf(u.z); tmp[3] = f2bf(u.w);
          tmp[4] = f2bf(v.x); tmp[5] = f2bf(v.y); tmp[6] = f2bf(v.z); tmp[7] = f2bf(v.w);
        } else {
          u32x4 v = *(const u32x4*)(B16 + idx);
          tmp[0] = (u16)(v.x & 0xffff); tmp[1] = (u16)(v.x >> 16);
          tmp[2] = (u16)(v.y & 0xffff); tmp[3] = (u16)(v.y >> 16);
          tmp[4] = (u16)(v.z & 0xffff); tmp[5] = (u16)(v.z >> 16);
          tmp[6] = (u16)(v.w & 0xffff); tmp[7] = (u16)(v.w >> 16);
        }
      } else {
#pragma unroll
        for (int e = 0; e < 8; ++e) tmp[e] = 0;
      }
      int rot = tid & 7;
#pragma unroll
      for (int e = 0; e < 8; ++e) {
        int ee = (e + rot) & 7;
        Bs[(bn + ee) * LDS_S + bk] = tmp[ee];
      }
    }
    __syncthreads();
    {
      bf16x8 fa[2], fb[2];
      fa[0] = *(const bf16x8*)&As[(wm +      fm) * LDS_S + fq * 8];
      fa[1] = *(const bf16x8*)&As[(wm + 16 + fm) * LDS_S + fq * 8];
      fb[0] = *(const bf16x8*)&Bs[(wn +      fm) * LDS_S + fq * 8];
      fb[1] = *(const bf16x8*)&Bs[(wn + 16 + fm) * LDS_S + fq * 8];
#pragma unroll
      for (int mt = 0; mt < 2; ++mt)
#pragma unroll
        for (int nt = 0; nt < 2; ++nt)
          acc[mt][nt] = __builtin_amdgcn_mfma_f32_16x16x32_bf16(fa[mt], fb[nt], acc[mt][nt], 0, 0, 0);
    }
    __syncthreads();
  }
#pragma unroll
  for (int mt = 0; mt < 2; ++mt)
#pragma unroll
    for (int nt = 0; nt < 2; ++nt)
#pragma unroll
      for (int rr = 0; rr < 4; ++rr) {
        int gm = m0 + wm + mt * 16 + fq * 4 + rr;
        int gn = n0 + wn + nt * 16 + fm;
        if (gm < M && gn < N) {
          float v = alpha * acc[mt][nt][rr];
          if (obf) Cb[(long)zl * sC + (long)gm * ldc + gn] = f2bf(v);
          else     Cf[(long)zl * sC + (long)gm * ldc + gn] = v;
        }
      }
}

// ------------------------------------------------------------- row LN -------
__global__ __launch_bounds__(256) void ln_rows(
    const u16* __restrict__ in, const void* __restrict__ g, const void* __restrict__ b,
    void* __restrict__ out, int N, const int* __restrict__ dtf, int isfinal)
{
  const int f = dtf[0];
  long row = blockIdx.x;
  const u16* ip = in + row * N;
  int tid = threadIdx.x, lane = tid & 63, wave = tid >> 6;
  const int nv = N >> 3;
  float s1 = 0.f, s2 = 0.f;
  for (int c8 = tid; c8 < nv; c8 += 256) {
    u32x4 v = *(const u32x4*)(ip + c8 * 8);
    float e0 = bf2f((u16)(v.x & 0xffff)), e1 = bf2f((u16)(v.x >> 16));
    float e2 = bf2f((u16)(v.y & 0xffff)), e3 = bf2f((u16)(v.y >> 16));
    float e4 = bf2f((u16)(v.z & 0xffff)), e5 = bf2f((u16)(v.z >> 16));
    float e6 = bf2f((u16)(v.w & 0xffff)), e7 = bf2f((u16)(v.w >> 16));
    s1 += ((e0 + e1) + (e2 + e3)) + ((e4 + e5) + (e6 + e7));
    s2 += ((e0*e0 + e1*e1) + (e2*e2 + e3*e3)) + ((e4*e4 + e5*e5) + (e6*e6 + e7*e7));
  }
#pragma unroll
  for (int o = 32; o; o >>= 1) { s1 += __shfl_xor(s1, o, 64); s2 += __shfl_xor(s2, o, 64); }
  __shared__ float red[8];
  if (lane == 0) { red[wave] = s1; red[4 + wave] = s2; }
  __syncthreads();
  s1 = red[0] + red[1] + red[2] + red[3];
  s2 = red[4] + red[5] + red[6] + red[7];
  float mean = s1 / N;
  float var = s2 / N - mean * mean;
  float rstd = rsqrtf(fmaxf(var, 0.f) + 1e-5f);
  for (int c8 = tid; c8 < nv; c8 += 256) {
    int c = c8 * 8;
    u32x4 v = *(const u32x4*)(ip + c);
    float e[8];
    e[0] = bf2f((u16)(v.x & 0xffff)); e[1] = bf2f((u16)(v.x >> 16));
    e[2] = bf2f((u16)(v.y & 0xffff)); e[3] = bf2f((u16)(v.y >> 16));
    e[4] = bf2f((u16)(v.z & 0xffff)); e[5] = bf2f((u16)(v.z >> 16));
    e[6] = bf2f((u16)(v.w & 0xffff)); e[7] = bf2f((u16)(v.w >> 16));
    float gg[8], bb[8];
    if (f) {
      const float* gp = (const float*)g + c; const float* bp = (const float*)b + c;
      f32x4 g0 = *(const f32x4*)gp, g1 = *(const f32x4*)(gp + 4);
      f32x4 b0 = *(const f32x4*)bp, b1 = *(const f32x4*)(bp + 4);
      gg[0]=g0.x; gg[1]=g0.y; gg[2]=g0.z; gg[3]=g0.w; gg[4]=g1.x; gg[5]=g1.y; gg[6]=g1.z; gg[7]=g1.w;
      bb[0]=b0.x; bb[1]=b0.y; bb[2]=b0.z; bb[3]=b0.w; bb[4]=b1.x; bb[5]=b1.y; bb[6]=b1.z; bb[7]=b1.w;
    } else {
      u32x4 gv = *(const u32x4*)((const u16*)g + c);
      u32x4 bv = *(const u32x4*)((const u16*)b + c);
      gg[0]=bf2f((u16)(gv.x&0xffff)); gg[1]=bf2f((u16)(gv.x>>16));
      gg[2]=bf2f((u16)(gv.y&0xffff)); gg[3]=bf2f((u16)(gv.y>>16));
      gg[4]=bf2f((u16)(gv.z&0xffff)); gg[5]=bf2f((u16)(gv.z>>16));
      gg[6]=bf2f((u16)(gv.w&0xffff)); gg[7]=bf2f((u16)(gv.w>>16));
      bb[0]=bf2f((u16)(bv.x&0xffff)); bb[1]=bf2f((u16)(bv.x>>16));
      bb[2]=bf2f((u16)(bv.y&0xffff)); bb[3]=bf2f((u16)(bv.y>>16));
      bb[4]=bf2f((u16)(bv.z&0xffff)); bb[5]=bf2f((u16)(bv.z>>16));
      bb[6]=bf2f((u16)(bv.w&0xffff)); bb[7]=bf2f((u16)(bv.w>>16));
    }
    float o_[8];
#pragma unroll
    for (int e2i = 0; e2i < 8; ++e2i) o_[e2i] = (e[e2i] - mean) * rstd * gg[e2i] + bb[e2i];
    if (isfinal && f) {
      float* op = (float*)out + row * N + c;
      f32x4 o0 = {o_[0], o_[1], o_[2], o_[3]}, o1 = {o_[4], o_[5], o_[6], o_[7]};
      *(f32x4*)op = o0; *(f32x4*)(op + 4) = o1;
    } else {
      u32x4 q = { (u32)f2bf(o_[0]) | ((u32)f2bf(o_[1]) << 16),
                  (u32)f2bf(o_[2]) | ((u32)f2bf(o_[3]) << 16),
                  (u32)f2bf(o_[4]) | ((u32)f2bf(o_[5]) << 16),
                  (u32)f2bf(o_[6]) | ((u32)f2bf(o_[7]) << 16) };
      *(u32x4*)((u16*)out + row * N + c) = q;
    }
  }
}

// ------------------------------------------------------------- wbar ---------
__global__ __launch_bounds__(256) void wbar_k(const void* __restrict__ Wconv,
                                              float* __restrict__ wbar,
                                              const int* __restrict__ dtf)
{
  const int f = dtf[0];
  int r = blockIdx.x * 4 + (threadIdx.x >> 6);
  int lane = threadIdx.x & 63;
  long base = (long)r * 768;
  float s = 0.f;
  for (int c = lane; c < 768; c += 64) s += gld(Wconv, base + c, f);
#pragma unroll
  for (int o = 32; o; o >>= 1) s += __shfl_xor(s, o, 64);
  if (lane == 0) wbar[r] = s * (1.f / 768.f);
}

// ------------------------------------------------------------- stats2 -------
// single pass over all 1028 (b,j) rows (de-chunked: full Y buffer)
__global__ __launch_bounds__(256) void stats2_k(
    const u16* __restrict__ midbf, const u16* __restrict__ Y, const float* __restrict__ wbar,
    u16* __restrict__ midi, float* __restrict__ pim)
{
  int g = blockIdx.y;
  int r = blockIdx.x * 4 + (threadIdx.x >> 6);   // 0..1027 (grid.x = 257)
  int lane = threadIdx.x & 63;
  int b = r / 257, j = r - b * 257;
  float m = bf2f(midbf[(long)r * 6656 + g * 64 + lane]);
  float y = bf2f(Y[((long)g * 1028 + r) * 64 + lane]);
  float wb = wbar[g * 64 + lane];
  float mup = m * wb, q2p = m * y;
#pragma unroll
  for (int o = 32; o; o >>= 1) { mup += __shfl_xor(mup, o, 64); q2p += __shfl_xor(q2p, o, 64); }
  float var = q2p - mup * mup;
  float inv = rsqrtf(fmaxf(var, 0.f) + 1e-5f);
  long base = ((long)b * 104 + g) * 257 + j;
  midi[base * 64 + lane] = f2bf(inv * m);
  if (lane == 0) pim[base] = inv * mup;
}

// ------------------------------------------------------------- softmax ------
__global__ __launch_bounds__(256) void softmax_k(
    const float* __restrict__ simf, const float* __restrict__ pim,
    u16* __restrict__ Abf, u16* __restrict__ A2bf, float* __restrict__ s_sh)
{
  int bh = blockIdx.x;
  int b = bh / 6, h = bh - b * 6;
  int tid = threadIdx.x, lane = tid & 63, wave = tid >> 6;
  int i = blockIdx.y * 4 + wave;
  int g = i % 104, rq = i / 104;
  const float* sp_ = simf + ((long)bh * 416 + i) * 257;
  float s[5];
#pragma unroll
  for (int jc = 0; jc < 5; ++jc) {
    int j = jc * 64 + lane;
    s[jc] = (j < 257) ? sp_[j] : -1e30f;
  }
  float mx = -1e30f;
#pragma unroll
  for (int jc = 0; jc < 5; ++jc) mx = fmaxf(mx, s[jc]);
#pragma unroll
  for (int o = 32; o; o >>= 1) mx = fmaxf(mx, __shfl_xor(mx, o, 64));
  float p[5], sum = 0.f, sp = 0.f;
  long pimb = ((long)b * 104 + g) * 257;
#pragma unroll
  for (int jc = 0; jc < 5; ++jc) {
    int j = jc * 64 + lane;
    float pv = 0.f;
    if (j < 257) { pv = __expf(s[jc] - mx); sp = fmaf(pv, pim[pimb + j], sp); }
    p[jc] = pv; sum += pv;
  }
#pragma unroll
  for (int o = 32; o; o >>= 1) { sum += __shfl_xor(sum, o, 64); sp += __shfl_xor(sp, o, 64); }
  float rs = 1.f / sum;
  long arow  = ((long)bh * 416 + i) * 264;
  long a2row = (((long)b * 104 + g) * 24 + h * 4 + rq) * 264;
#pragma unroll
  for (int jc = 0; jc < 5; ++jc) {
    int j = jc * 64 + lane;
    if (j < 257) { u16 pb = f2bf(p[jc] * rs); Abf[arow + j] = pb; A2bf[a2row + j] = pb; }
    else if (j < 264) { Abf[arow + j] = 0; A2bf[a2row + j] = 0; }
  }
  if (lane == 0) s_sh[(long)bh * 416 + i] = sp * rs;
}

// -------------------------------------------------- fused O-gemm + combine --
// combine only consumes O[r=h*4+rq][d] at d in [h*128, h*128+128): compute just
// those slices. One block per z=(b,g); T (24x64) in LDS; W column reads are
// lane-coalesced; epilogue (gv2/bv2/s_sh/c_buf) applied in-register.
__global__ __launch_bounds__(256) void oc_k(
    const u16* __restrict__ T, const u16* __restrict__ Wb,
    const float* __restrict__ s_sh, const float* __restrict__ c_buf,
    const void* __restrict__ gv2, const void* __restrict__ bv2,
    u16* __restrict__ opbf, const int* __restrict__ dtf)
{
  const int f = dtf[0];
  int z = blockIdx.x;                 // b*104+g
  int b = z / 104, g = z - b * 104;
  int tid = threadIdx.x;
  __shared__ float Ts[24][64];        // 6 KB
  const u16* tp = T + (long)z * 1536;
  for (int idx = tid; idx < 1536; idx += 256) Ts[idx >> 6][idx & 63] = bf2f(tp[idx]);
  __syncthreads();
  const int dh = tid & 127;
  const int hbase = (tid >> 7) * 3;   // threads 0..127 -> h 0..2, 128..255 -> h 3..5
  const u16* wg = Wb + (long)g * 49152;
#pragma unroll
  for (int hh = 0; hh < 3; ++hh) {
    int h = hbase + hh;
    int d = h * 128 + dh;
    const u16* wp = wg + d;
    float a0 = 0.f, a1 = 0.f, a2 = 0.f, a3 = 0.f;
#pragma unroll 16
    for (int k = 0; k < 64; ++k) {
      float w = bf2f(wp[(long)k * 768]);
      a0 = fmaf(Ts[h * 4 + 0][k], w, a0);
      a1 = fmaf(Ts[h * 4 + 1][k], w, a1);
      a2 = fmaf(Ts[h * 4 + 2][k], w, a2);
      a3 = fmaf(Ts[h * 4 + 3][k], w, a3);
    }
    float acc[4] = {a0, a1, a2, a3};
    float gvd = gld(gv2, d, f), bvd = gld(bv2, d, f);
#pragma unroll
    for (int rq = 0; rq < 4; ++rq) {
      int i = rq * 104 + g;
      float ssh = s_sh[((long)b * 6 + h) * 416 + i];
      float val = gvd * (acc[rq] - ssh) + bvd
                + c_buf[(((long)b * 6 + h) * 416 + i) * 128 + dh];
      opbf[((long)b * 416 + i) * 768 + d] = f2bf(val);
    }
  }
}

// ---------------------------------------------------------------- host ------
static void launch_gemm(const void* A, const void* B, float* Cf, u16* Cb, int obf,
                        int M, int N, int K, int lda, int ldb, int ldc,
                        long sAo, long sAi, int adiv, long sBo, long sBi, int bdiv,
                        long sC, int zoff, int Z, int btrans, float alpha,
                        const int* dtf, int aSel, int bSel, hipStream_t st)
{
  dim3 grid((M + 63) / 64, (N + 63) / 64, Z);
  gemm_bf16<<<grid, dim3(256), 0, st>>>(A, B, Cf, Cb, obf, M, N, K, lda, ldb, ldc,
                                        sAo, sAi, adiv, sBo, sBi, bdiv,
                                        sC, zoff, btrans, alpha, dtf, aSel, bSel);
}

static void launch_gemm128(const u16* A, const u16* B, u16* C,
                           int M, int N, int K, hipStream_t st)
{
  dim3 grid((M + 127) / 128, N / 128, 1);
  gemm128<<<grid, dim3(256), 0, st>>>(A, B, C, M, N, K, K, K, N);
}

extern "C" void kernel_launch(void* const* d_in, const int* in_sizes, int n_in,
                              void* d_out, int out_size, void* d_ws, size_t ws_size,
                              hipStream_t stream)
{
  (void)in_sizes; (void)n_in;
  const void* x   = d_in[0];
  const void* ctx = d_in[1];
  const void* Wq  = d_in[2];
  const void* gq  = d_in[3];
  const void* bq  = d_in[4];
  const void* Wk  = d_in[5];
  const void* gk  = d_in[6];
  const void* bk  = d_in[7];
  const void* Wv  = d_in[8];
  const void* gv1 = d_in[9];
  const void* bv1 = d_in[10];
  const void* Wcv = d_in[11];
  const void* gv2 = d_in[12];
  const void* bv2 = d_in[13];
  const void* Wo  = d_in[14];
  const void* go  = d_in[15];
  const void* bo  = d_in[16];

  // -------- workspace layout (R9 base kept intact; new dedicated bufs appended) --------
  const size_t SZ_FLAG = 256;
  const size_t SZ_QBF  = 2555904;
  const size_t SZ_KBF  = 1579008;
  const size_t SZ_MID  = 13684736;
  const size_t SZ_MM   = 1703936;
  const size_t SZ_WB   = 26624;
  const size_t SZ_MIDI = 13684736;
  const size_t SZ_PIM  = 427648;
  const size_t SZ_ABF  = 5271552;
  const size_t SZ_A2   = 5271552;
  const size_t SZ_SSH  = 39936;
  const size_t SZ_CB   = 1579008;
  const size_t SZ_WCVB = 10223616;   // 104*64*768 bf16
  const size_t SZ_YF   = 13684736;   // 104*1028*64 bf16 (full, de-chunked)
  const size_t SZ_WT   = 1179648;    // 768*768 bf16 (x3: WqT, WkT, WoT)
  const size_t REQUIRED = SZ_FLAG + SZ_QBF + SZ_KBF + SZ_MID + SZ_MM + SZ_WB +
                          SZ_MIDI + SZ_PIM + SZ_ABF + SZ_A2 + SZ_SSH + SZ_CB +
                          SZ_WCVB + SZ_YF + 3 * SZ_WT;   // 73,272,192

  if (ws_size < REQUIRED) {
    fill_k<<<(out_size + 255) / 256, 256, 0, stream>>>((u16*)d_out, (float)(ws_size >> 20), out_size);
    return;
  }

  char* p = (char*)d_ws;
  int*   dtf   = (int*)  p;                 p += SZ_FLAG;
  u16*   qbf   = (u16*)  p;                 p += SZ_QBF;
  u16*   kbf   = (u16*)  p;                 p += SZ_KBF;
  char*  midrg = p;                         p += SZ_MID;
  char*  mmrg  = p;                         p += SZ_MM;
  float* wbar  = (float*)p;                 p += SZ_WB;
  u16*   midi  = (u16*)  p;                 p += SZ_MIDI;
  float* pim   = (float*)p;                 p += SZ_PIM;
  char*  abfrg = p;                         p += SZ_ABF;
  u16*   A2bf  = (u16*)  p;                 p += SZ_A2;
  float* s_sh  = (float*)p;                 p += SZ_SSH;
  u16*   cb    = (u16*)  p;                 p += SZ_CB;
  u16*   wcvb  = (u16*)  p;                 p += SZ_WCVB;
  u16*   yfull = (u16*)  p;                 p += SZ_YF;
  u16*   wqt2  = (u16*)  p;                 p += SZ_WT;
  u16*   wkt2  = (u16*)  p;                 p += SZ_WT;
  u16*   wot2  = (u16*)  p;                 p += SZ_WT;

  u16*   midbf = (u16*)midrg;
  float* simf  = (float*)midrg;
  float* c_buf = (float*)midrg;
  u16*   Tb16  = (u16*)(midrg + 5111808);
  u16*   Gb    = (u16*)mmrg;
  u16*   xb    = (u16*)abfrg;
  u16*   WvT   = (u16*)abfrg;   // spans abfrg+A2bf (both dead at that time)
  u16*   Abf   = (u16*)abfrg;
  u16*   opbf  = (u16*)abfrg;

  probe_k<<<1, 256, 0, stream>>>((const u32*)x, dtf);

  // ---- prep: bf16 copies (x, ctx, Wconv) + the three 768^2 transposes ----
  {
    const int n0_ = 1277952, n1_ = 789504, n2_ = 5111808;  // all %8 == 0
    int blocks = ((n0_ + n1_ + n2_) / 8 + 255) / 256;
    convb3_k<<<blocks, 256, 0, stream>>>(x, xb, n0_, ctx, cb, n1_, Wcv, wcvb, n2_, dtf);
  }
  transb3_k<<<dim3(24, 24, 3), 256, 0, stream>>>(Wq, Wk, Wo, wqt2, wkt2, wot2, dtf);

  // q = LN(x @ Wq)
  launch_gemm128(xb, wqt2, qbf, 1664, 768, 768, stream);
  ln_rows<<<1664, 256, 0, stream>>>(qbf, gq, bq, qbf, 768, dtf, 0);

  // k = LN(ctx @ Wk)
  launch_gemm128(cb, wkt2, kbf, 1028, 768, 768, stream);
  ln_rows<<<1028, 256, 0, stream>>>(kbf, gk, bk, kbf, 768, dtf, 0);

  transb_k<<<dim3(208, 24), 256, 0, stream>>>(Wv, WvT, 768, 6656, dtf);
  // mid = LN(ctx @ Wv)
  launch_gemm128(cb, WvT, midbf, 1028, 6656, 768, stream);
  ln_rows<<<1028, 256, 0, stream>>>(midbf, gv1, bv1, midbf, 6656, dtf, 0);

  // Gram: M[g] = Wconv[g] @ Wconv[g]^T / 768  (bf16 inputs -> fast staging path)
  launch_gemm(wcvb, wcvb, nullptr, Gb, 1, 64, 64, 768, 768, 768, 64,
              49152, 0, 1, 49152, 0, 1, 4096, 0, 104, 1, 1.f / 768.f, dtf, 0, 0, stream);
  wbar_k<<<1664, 256, 0, stream>>>(Wcv, wbar, dtf);
  // stats via MFMA: Y = mid_g @ M[g], single shot over all 1028 rows
  launch_gemm(midbf, Gb, nullptr, yfull, 1,
              1028, 64, 64, 6656, 64, 64,
              0, 64, 104, 4096, 0, 1, 65792, 0, 104, 1, 1.f, dtf, 0, 0, stream);
  stats2_k<<<dim3(257, 104), 256, 0, stream>>>(midbf, yfull, wbar, midi, pim);

  // sim = scale^2 * q @ k^T   (z = b*6+h, btrans, fp32 out)
  launch_gemm(qbf, kbf, simf, nullptr, 0, 416, 257, 128, 768, 768, 257,
              319488, 128, 6, 197376, 128, 6, 106912, 0, 24, 1,
              0.08838834764831845f, dtf, 0, 0, stream);
  softmax_k<<<dim3(24, 104), 256, 0, stream>>>(simf, pim, Abf, A2bf, s_sh);

  // c = A @ ctx_head   (z = b*6+h; B = cb bf16)
  launch_gemm(Abf, cb, c_buf, nullptr, 0, 416, 128, 257, 264, 768, 128,
              109824, 0, 1, 197376, 128, 6, 53248, 0, 24, 0, 1.f, dtf, 0, 0, stream);
  // T = A2 @ midi      (z = b*104+g)
  launch_gemm(A2bf, midi, nullptr, Tb16, 1, 24, 64, 257, 264, 64, 64,
              6336, 0, 1, 16448, 0, 1, 1536, 0, 416, 0, 1.f, dtf, 0, 0, stream);

  // fused O-gemm + combine: only the consumed head-diagonal slices computed
  oc_k<<<416, 256, 0, stream>>>(Tb16, wcvb, s_sh, c_buf, gv2, bv2, opbf, dtf);

  // out = LN(out_pre @ Wo): GEMM -> qbf scratch, LN -> d_out (flag dtype)
  launch_gemm128(opbf, wot2, qbf, 1664, 768, 768, stream);
  ln_rows<<<1664, 256, 0, stream>>>(qbf, go, bo, d_out, 768, dtf, 1);
}

// Round 3
// 309.122 us; speedup vs baseline: 1.3004x; 1.1616x over previous
//
#include <hip/hip_runtime.h>

// SubjBasisGenerator fused pipeline. B=4 NQ=416 NC=257 D=768 H=6 DH=128 G=104 R=4 LORA=64
// R13 == R12 resubmit (round 2 bench was an infra failure, no counters; audit
//      found no OOB/hang vector — one lever per bench, so no code change).
// R12: (1) q/k/mid gemm128s merged into one launch (mgemm3), B-panel-major tile
//      order for mid (consecutive blocks share B panel -> L2 reuse, ~80MB less
//      HBM re-read) and q/k/mid overlap instead of serializing underfilled grids.
//      (2) three LNs merged (mln3); all transposes merged (transM: Wq/Wk/Wo/Wv
//      + per-batch ctx^T [768][264] zero-padded).
//      (3) c-GEMM now btrans fast-vector path via ctx^T; K padded 257->264 for
//      c/T GEMMs (midi padded to 264 rows, pads zeroed in convb4 -> no scalar
//      guarded tails). wbar reads bf16 Wconv. 21 -> 16 dispatches.
// R11: oc_k fusion (O-gemm+combine), Wconv bf16 pre-convert, Y de-chunked.
// R10: big row-major GEMMs on gemm128 — 128x128 tile, 4x4 MFMA acc/wave,
//      global_load_lds width-16 async staging.
//
// Algebra: the grouped-conv+LN v-path decomposes exactly (no (B,G,NC,768) tensor):
//   sum_j A_j v_j = gv2*( (sum_j A_j inv_j mid_j)@Wconv[g] - sum_j A_j inv_j mu_j )
//                   + bv2 + (A @ ctx)
//   q2[b,g,j] = mid^T M[g] mid = mid . (M[g] @ mid),  M[g] = Wconv[g]Wconv[g]^T/768

typedef unsigned short u16;
typedef unsigned int   u32;
typedef __attribute__((ext_vector_type(4))) float f32x4;
typedef __attribute__((ext_vector_type(4))) u32   u32x4;
typedef __attribute__((ext_vector_type(8))) short bf16x8;

__device__ __forceinline__ float bf2f(u16 v) { return __uint_as_float(((u32)v) << 16); }
__device__ __forceinline__ u16 f2bf(float f) {
  u32 u = __float_as_uint(f);
  u32 r = u + 0x7fffu + ((u >> 16) & 1u);  // RNE
  return (u16)(r >> 16);
}
__device__ __forceinline__ float gld(const void* p, long idx, int f32) {
  return f32 ? ((const float*)p)[idx] : bf2f(((const u16*)p)[idx]);
}

typedef const __attribute__((address_space(1))) u32 gas_u32;
typedef __attribute__((address_space(3))) u32 las_u32;

// async 16B/lane global->LDS; LDS dest = wave-uniform base + lane*16 (m97).
__device__ __forceinline__ void stage16(const u16* g, u16* lbase, int lane) {
#if __has_builtin(__builtin_amdgcn_global_load_lds)
  (void)lane;
  __builtin_amdgcn_global_load_lds((gas_u32*)g, (las_u32*)lbase, 16, 0, 0);
#else
  *(u32x4*)(lbase + lane * 8) = *(const u32x4*)g;
#endif
}

// ------------------------------------------------------------ dtype probe ---
__global__ __launch_bounds__(256) void probe_k(const u32* __restrict__ xw, int* __restrict__ flag) {
  int tid = threadIdx.x, c = 0;
  for (int i = tid; i < 4096; i += 256) {
    u16 lo = (u16)(xw[i] & 0xffffu);
    float a = fabsf(bf2f(lo));
    if (lo == 0 || (a >= 1e-3f && a <= 32.f)) ++c;
  }
#pragma unroll
  for (int o = 32; o; o >>= 1) c += __shfl_xor(c, o, 64);
  __shared__ int r[4];
  if ((tid & 63) == 0) r[tid >> 6] = c;
  __syncthreads();
  if (tid == 0) flag[0] = (r[0] + r[1] + r[2] + r[3] >= 2048) ? 0 : 1;  // 1 = fp32
}

// ------------------------------------------------------------ diag fill -----
__global__ __launch_bounds__(256) void fill_k(u16* p, float v, int n) {
  int i = blockIdx.x * 256 + threadIdx.x;
  if (i < n) p[i] = f2bf(v);
}

// ---------------- ext -> bf16 copy (x, ctx, Wconv) + midi pad-row zeroing ---
__global__ __launch_bounds__(256) void convb4_k(
    const void* __restrict__ s0, u16* __restrict__ d0, int n0_,
    const void* __restrict__ s1, u16* __restrict__ d1, int n1_,
    const void* __restrict__ s2, u16* __restrict__ d2, int n2_,
    u16* __restrict__ midi, int n3_,
    const int* __restrict__ dtf)
{
  const int f = dtf[0];
  long i = ((long)blockIdx.x * 256 + threadIdx.x) * 8;
  const long t0 = n0_, t1 = t0 + n1_, t2 = t1 + n2_, t3 = t2 + n3_;
  if (i >= t3) return;
  if (i >= t2) {
    // zero the 7 pad rows (j=257..263) of each of the 416 midi z-blocks
    long e = i - t2;                 // multiple of 8, 448 elems per z
    long z = e / 448, off = e - z * 448;
    u32x4 zz = {0u, 0u, 0u, 0u};
    *(u32x4*)(midi + z * 16896 + 16448 + off) = zz;
    return;
  }
  const void* in; u16* out;
  if (i < t0)      { in = s0; out = d0; }
  else if (i < t1) { in = s1; out = d1; i -= t0; }
  else             { in = s2; out = d2; i -= t1; }
  if (f) {
    const float* ip = (const float*)in + i;
    f32x4 a = *(const f32x4*)ip, b = *(const f32x4*)(ip + 4);
    u32x4 q = { (u32)f2bf(a.x) | ((u32)f2bf(a.y) << 16),
                (u32)f2bf(a.z) | ((u32)f2bf(a.w) << 16),
                (u32)f2bf(b.x) | ((u32)f2bf(b.y) << 16),
                (u32)f2bf(b.z) | ((u32)f2bf(b.w) << 16) };
    *(u32x4*)(out + i) = q;
  } else {
    *(u32x4*)(out + i) = *(const u32x4*)((const u16*)in + i);
  }
}

// ---------------- merged transposes: Wq/Wk/Wo (768^2), Wv (768x6656), -------
// ---------------- ctx^T per b: [257][768] -> [768][264] zero-padded ---------
__global__ __launch_bounds__(256) void transM_k(
    const void* __restrict__ Wq, const void* __restrict__ Wk, const void* __restrict__ Wo,
    const void* __restrict__ Wv, const void* __restrict__ ctx,
    u16* __restrict__ wqt, u16* __restrict__ wkt, u16* __restrict__ wot,
    u16* __restrict__ wvt, u16* __restrict__ ctxT,
    const int* __restrict__ dtf)
{
  const int f = dtf[0];
  int t = blockIdx.x;
  const void* in; u16* out;
  int inK, inN, ldo, outK, nx;
  long inBase = 0, outBase = 0;
  if (t < 1728) {                    // 3 x 768x768 weights: 576 tiles each
    int w = t / 576; t -= w * 576;
    in  = w == 0 ? Wq : w == 1 ? Wk : Wo;
    out = w == 0 ? wqt : w == 1 ? wkt : wot;
    inK = 768; inN = 768; ldo = 768; outK = 768; nx = 24;
  } else if (t < 6720) {             // Wv 768x6656: 208 n-tiles x 24 k-tiles
    t -= 1728;
    in = Wv; out = wvt;
    inK = 768; inN = 6656; ldo = 768; outK = 768; nx = 208;
  } else {                           // ctxT: 4 b x (24 n-tiles x 9 k-tiles)
    t -= 6720;
    int b = t / 216; t -= b * 216;
    in = ctx; out = ctxT;
    inK = 257; inN = 768; ldo = 264; outK = 264; nx = 24;
    inBase = (long)b * 257 * 768; outBase = (long)b * 768 * 264;
  }
  int n0 = (t % nx) * 32, k0 = (t / nx) * 32;
  __shared__ float s[32][33];
  int tx = threadIdx.x & 31, ty = threadIdx.x >> 5;  // 32 x 8
#pragma unroll
  for (int i = 0; i < 32; i += 8) {
    int k = k0 + ty + i, n = n0 + tx;
    float v = 0.f;
    if (k < inK && n < inN) v = gld(in, inBase + (long)k * inN + n, f);
    s[ty + i][tx] = v;
  }
  __syncthreads();
#pragma unroll
  for (int i = 0; i < 32; i += 8) {
    int n = n0 + ty + i, k = k0 + tx;
    if (n < inN && k < outK) out[outBase + (long)n * ldo + k] = f2bf(s[tx][ty + i]);
  }
}

// ------------------------------------------------------------- gemm128 ------
// C_bf16 = A_bf16[M,K] @ B_bf16[N,K]^T. Requires N%128==0, K%32==0; M-tail via
// row-clamped staging + guarded writes. 128x128 tile, BK=32, 4 waves each 64x64
// (4x4 mfma_f32_16x16x32_bf16). LDS unpadded [row][32] fed by stage16.
__device__ __forceinline__ void gemm128_body(
    const u16* __restrict__ A, const u16* __restrict__ B, u16* __restrict__ C,
    int M, int N, int K, int lda, int ldb, int ldc, int m0, int n0)
{
  __shared__ __attribute__((aligned(16))) u16 As[128 * 32];
  __shared__ __attribute__((aligned(16))) u16 Bs[128 * 32];
  const int tid = threadIdx.x, lane = tid & 63, wave = tid >> 6;
  const int wm = (wave >> 1) * 64, wn = (wave & 1) * 64;
  const int fm = lane & 15, fq = lane >> 4;

  const int srow = lane >> 2, selem = (lane & 3) * 8;
  int ra1 = m0 + wave * 16 + srow;      if (ra1 > M - 1) ra1 = M - 1;
  int ra2 = m0 + 64 + wave * 16 + srow; if (ra2 > M - 1) ra2 = M - 1;
  const int rb1 = n0 + wave * 16 + srow;
  const int rb2 = n0 + 64 + wave * 16 + srow;
  const u16* pa1 = A + (long)ra1 * lda + selem;
  const u16* pa2 = A + (long)ra2 * lda + selem;
  const u16* pb1 = B + (long)rb1 * ldb + selem;
  const u16* pb2 = B + (long)rb2 * ldb + selem;
  u16* la1 = As + wave * 512;
  u16* la2 = As + 2048 + wave * 512;
  u16* lb1 = Bs + wave * 512;
  u16* lb2 = Bs + 2048 + wave * 512;

  f32x4 acc[4][4];
  const f32x4 zero4 = {0.f, 0.f, 0.f, 0.f};
#pragma unroll
  for (int a_ = 0; a_ < 4; ++a_)
#pragma unroll
    for (int b_ = 0; b_ < 4; ++b_) acc[a_][b_] = zero4;

  for (int k0 = 0; k0 < K; k0 += 32) {
    stage16(pa1, la1, lane);
    stage16(pa2, la2, lane);
    stage16(pb1, lb1, lane);
    stage16(pb2, lb2, lane);
    pa1 += 32; pa2 += 32; pb1 += 32; pb2 += 32;
    __syncthreads();
    bf16x8 fa[4], fb[4];
#pragma unroll
    for (int mt = 0; mt < 4; ++mt)
      fa[mt] = *(const bf16x8*)&As[(wm + mt * 16 + fm) * 32 + fq * 8];
#pragma unroll
    for (int nt = 0; nt < 4; ++nt)
      fb[nt] = *(const bf16x8*)&Bs[(wn + nt * 16 + fm) * 32 + fq * 8];
#pragma unroll
    for (int mt = 0; mt < 4; ++mt)
#pragma unroll
      for (int nt = 0; nt < 4; ++nt)
        acc[mt][nt] = __builtin_amdgcn_mfma_f32_16x16x32_bf16(fa[mt], fb[nt], acc[mt][nt], 0, 0, 0);
    __syncthreads();
  }
#pragma unroll
  for (int mt = 0; mt < 4; ++mt)
#pragma unroll
    for (int nt = 0; nt < 4; ++nt)
#pragma unroll
      for (int rr = 0; rr < 4; ++rr) {
        int gm = m0 + wm + mt * 16 + fq * 4 + rr;
        int gn = n0 + wn + nt * 16 + fm;
        if (gm < M) C[(long)gm * ldc + gn] = f2bf(acc[mt][nt][rr]);
      }
}

__global__ __launch_bounds__(256) void gemm128(
    const u16* __restrict__ A, const u16* __restrict__ B, u16* __restrict__ C,
    int M, int N, int K, int lda, int ldb, int ldc)
{
  gemm128_body(A, B, C, M, N, K, lda, ldb, ldc, blockIdx.x * 128, blockIdx.y * 128);
}

// merged q/k/mid: one launch, m-fastest tile order (consecutive blocks share
// the B panel -> L2 reuse for mid's 10MB B, and the 3 gemms overlap).
__global__ __launch_bounds__(256) void mgemm3_k(
    const u16* __restrict__ Aq, const u16* __restrict__ Bq, u16* __restrict__ Cq,
    const u16* __restrict__ Ak, const u16* __restrict__ Bk, u16* __restrict__ Ck,
    const u16* __restrict__ Am, const u16* __restrict__ Bm, u16* __restrict__ Cm)
{
  int bid = blockIdx.x;
  const u16 *A, *B; u16* C; int M, N, lid, mx;
  if (bid < 78)       { A = Aq; B = Bq; C = Cq; M = 1664; N = 768;  lid = bid;       mx = 13; }
  else if (bid < 132) { A = Ak; B = Bk; C = Ck; M = 1028; N = 768;  lid = bid - 78;  mx = 9;  }
  else                { A = Am; B = Bm; C = Cm; M = 1028; N = 6656; lid = bid - 132; mx = 9;  }
  int m0 = (lid % mx) * 128, n0 = (lid / mx) * 128;
  gemm128_body(A, B, C, M, N, 768, 768, 768, N, m0, n0);
}

// ---------------------------------------------------------------- GEMM ------
// (64x64 general kernel — batched / flag-dtype / fp32-out cases)
#define LDS_S 40

__global__ __launch_bounds__(256) void gemm_bf16(
    const void* __restrict__ A, const void* __restrict__ B,
    float* __restrict__ Cf, u16* __restrict__ Cb, int obf,
    int M, int N, int K, int lda, int ldb, int ldc,
    long sAo, long sAi, int adiv, long sBo, long sBi, int bdiv,
    long sC, int zoff, int btrans, float alpha,
    const int* __restrict__ dtf, int aSel, int bSel)
{
  const int f = dtf[0];
  const int af32 = aSel & f, bf32 = bSel & f;
  const int zl = blockIdx.z, zg = zl + zoff;
  const long aoff = (long)(zg / adiv) * sAo + (long)(zg % adiv) * sAi;
  const long boff = (long)(zg / bdiv) * sBo + (long)(zg % bdiv) * sBi;
  const u16*   A16 = (const u16*)A + aoff;
  const float* A32 = (const float*)A + aoff;
  const u16*   B16 = (const u16*)B + boff;
  const float* B32 = (const float*)B + boff;

  __shared__ __attribute__((aligned(16))) u16 As[64 * LDS_S];
  __shared__ __attribute__((aligned(16))) u16 Bs[64 * LDS_S];

  const int tid = threadIdx.x;
  const int lane = tid & 63, wave = tid >> 6;
  const int m0 = blockIdx.x * 64, n0 = blockIdx.y * 64;
  const int wm = (wave >> 1) * 32, wn = (wave & 1) * 32;
  const int fm = lane & 15, fq = lane >> 4;

  const int ar = tid >> 2, ak = (tid & 3) * 8;
  const int bk = tid >> 3, bn = (tid & 7) * 8;

  f32x4 acc[2][2];
  const f32x4 zero4 = {0.f, 0.f, 0.f, 0.f};
#pragma unroll
  for (int a_ = 0; a_ < 2; ++a_)
#pragma unroll
    for (int b_ = 0; b_ < 2; ++b_) acc[a_][b_] = zero4;

  for (int k0 = 0; k0 < K; k0 += 32) {
    {
      int gm = m0 + ar, gk = k0 + ak;
      long idx = (long)gm * lda + gk;
      if (gm < M && gk + 8 <= K) {
        if (af32) {
          f32x4 u = *(const f32x4*)(A32 + idx), v = *(const f32x4*)(A32 + idx + 4);
          u32x4 q = { (u32)f2bf(u.x) | ((u32)f2bf(u.y) << 16),
                      (u32)f2bf(u.z) | ((u32)f2bf(u.w) << 16),
                      (u32)f2bf(v.x) | ((u32)f2bf(v.y) << 16),
                      (u32)f2bf(v.z) | ((u32)f2bf(v.w) << 16) };
          *(u32x4*)&As[ar * LDS_S + ak] = q;
        } else {
          *(u32x4*)&As[ar * LDS_S + ak] = *(const u32x4*)(A16 + idx);
        }
      } else {
#pragma unroll
        for (int e = 0; e < 8; ++e) {
          u16 v = 0;
          if (gm < M && gk + e < K) v = f2bf(gld(A, aoff + idx + e, af32));
          As[ar * LDS_S + ak + e] = v;
        }
      }
    }
    if (btrans) {
      int gn = n0 + ar, gk = k0 + ak;
      long idx = (long)gn * ldb + gk;
      if (gn < N && gk + 8 <= K) {
        if (bf32) {
          f32x4 u = *(const f32x4*)(B32 + idx), v = *(const f32x4*)(B32 + idx + 4);
          u32x4 q = { (u32)f2bf(u.x) | ((u32)f2bf(u.y) << 16),
                      (u32)f2bf(u.z) | ((u32)f2bf(u.w) << 16),
                      (u32)f2bf(v.x) | ((u32)f2bf(v.y) << 16),
                      (u32)f2bf(v.z) | ((u32)f2bf(v.w) << 16) };
          *(u32x4*)&Bs[ar * LDS_S + ak] = q;
        } else {
          *(u32x4*)&Bs[ar * LDS_S + ak] = *(const u32x4*)(B16 + idx);
        }
      } else {
#pragma unroll
        for (int e = 0; e < 8; ++e) {
          u16 v = 0;
          if (gn < N && gk + e < K) v = f2bf(gld(B, boff + idx + e, bf32));
          Bs[ar * LDS_S + ak + e] = v;
        }
      }
    } else {
      int gk = k0 + bk;
      long idx = (long)gk * ldb + n0 + bn;
      u16 tmp[8];
      if (gk < K) {
        if (bf32) {
          f32x4 u = *(const f32x4*)(B32 + idx), v = *(const f32x4*)(B32 + idx + 4);
          tmp[0] = f2bf(u.x); tmp[1] = f2bf(u.y); tmp[2] = f2bf(u.z); tmp[3] = f2bf(u.w);
          tmp[4] = f2bf(v.x); tmp[5] = f2bf(v.y); tmp[6] = f2bf(v.z); tmp[7] = f2bf(v.w);
        } else {
          u32x4 v = *(const u32x4*)(B16 + idx);
          tmp[0] = (u16)(v.x & 0xffff); tmp[1] = (u16)(v.x >> 16);
          tmp[2] = (u16)(v.y & 0xffff); tmp[3] = (u16)(v.y >> 16);
          tmp[4] = (u16)(v.z & 0xffff); tmp[5] = (u16)(v.z >> 16);
          tmp[6] = (u16)(v.w & 0xffff); tmp[7] = (u16)(v.w >> 16);
        }
      } else {
#pragma unroll
        for (int e = 0; e < 8; ++e) tmp[e] = 0;
      }
      int rot = tid & 7;
#pragma unroll
      for (int e = 0; e < 8; ++e) {
        int ee = (e + rot) & 7;
        Bs[(bn + ee) * LDS_S + bk] = tmp[ee];
      }
    }
    __syncthreads();
    {
      bf16x8 fa[2], fb[2];
      fa[0] = *(const bf16x8*)&As[(wm +      fm) * LDS_S + fq * 8];
      fa[1] = *(const bf16x8*)&As[(wm + 16 + fm) * LDS_S + fq * 8];
      fb[0] = *(const bf16x8*)&Bs[(wn +      fm) * LDS_S + fq * 8];
      fb[1] = *(const bf16x8*)&Bs[(wn + 16 + fm) * LDS_S + fq * 8];
#pragma unroll
      for (int mt = 0; mt < 2; ++mt)
#pragma unroll
        for (int nt = 0; nt < 2; ++nt)
          acc[mt][nt] = __builtin_amdgcn_mfma_f32_16x16x32_bf16(fa[mt], fb[nt], acc[mt][nt], 0, 0, 0);
    }
    __syncthreads();
  }
#pragma unroll
  for (int mt = 0; mt < 2; ++mt)
#pragma unroll
    for (int nt = 0; nt < 2; ++nt)
#pragma unroll
      for (int rr = 0; rr < 4; ++rr) {
        int gm = m0 + wm + mt * 16 + fq * 4 + rr;
        int gn = n0 + wn + nt * 16 + fm;
        if (gm < M && gn < N) {
          float v = alpha * acc[mt][nt][rr];
          if (obf) Cb[(long)zl * sC + (long)gm * ldc + gn] = f2bf(v);
          else     Cf[(long)zl * sC + (long)gm * ldc + gn] = v;
        }
      }
}

// ------------------------------------------------------------- row LN -------
__device__ __forceinline__ void ln_row(
    const u16* __restrict__ ip, const void* __restrict__ g, const void* __restrict__ b,
    u16* __restrict__ ob, float* __restrict__ of, int N, int f)
{
  int tid = threadIdx.x, lane = tid & 63, wave = tid >> 6;
  const int nv = N >> 3;
  float s1 = 0.f, s2 = 0.f;
  for (int c8 = tid; c8 < nv; c8 += 256) {
    u32x4 v = *(const u32x4*)(ip + c8 * 8);
    float e0 = bf2f((u16)(v.x & 0xffff)), e1 = bf2f((u16)(v.x >> 16));
    float e2 = bf2f((u16)(v.y & 0xffff)), e3 = bf2f((u16)(v.y >> 16));
    float e4 = bf2f((u16)(v.z & 0xffff)), e5 = bf2f((u16)(v.z >> 16));
    float e6 = bf2f((u16)(v.w & 0xffff)), e7 = bf2f((u16)(v.w >> 16));
    s1 += ((e0 + e1) + (e2 + e3)) + ((e4 + e5) + (e6 + e7));
    s2 += ((e0*e0 + e1*e1) + (e2*e2 + e3*e3)) + ((e4*e4 + e5*e5) + (e6*e6 + e7*e7));
  }
#pragma unroll
  for (int o = 32; o; o >>= 1) { s1 += __shfl_xor(s1, o, 64); s2 += __shfl_xor(s2, o, 64); }
  __shared__ float red[8];
  if (lane == 0) { red[wave] = s1; red[4 + wave] = s2; }
  __syncthreads();
  s1 = red[0] + red[1] + red[2] + red[3];
  s2 = red[4] + red[5] + red[6] + red[7];
  float mean = s1 / N;
  float var = s2 / N - mean * mean;
  float rstd = rsqrtf(fmaxf(var, 0.f) + 1e-5f);
  for (int c8 = tid; c8 < nv; c8 += 256) {
    int c = c8 * 8;
    u32x4 v = *(const u32x4*)(ip + c);
    float e[8];
    e[0] = bf2f((u16)(v.x & 0xffff)); e[1] = bf2f((u16)(v.x >> 16));
    e[2] = bf2f((u16)(v.y & 0xffff)); e[3] = bf2f((u16)(v.y >> 16));
    e[4] = bf2f((u16)(v.z & 0xffff)); e[5] = bf2f((u16)(v.z >> 16));
    e[6] = bf2f((u16)(v.w & 0xffff)); e[7] = bf2f((u16)(v.w >> 16));
    float gg[8], bb[8];
    if (f) {
      const float* gp = (const float*)g + c; const float* bp = (const float*)b + c;
      f32x4 g0 = *(const f32x4*)gp, g1 = *(const f32x4*)(gp + 4);
      f32x4 b0 = *(const f32x4*)bp, b1 = *(const f32x4*)(bp + 4);
      gg[0]=g0.x; gg[1]=g0.y; gg[2]=g0.z; gg[3]=g0.w; gg[4]=g1.x; gg[5]=g1.y; gg[6]=g1.z; gg[7]=g1.w;
      bb[0]=b0.x; bb[1]=b0.y; bb[2]=b0.z; bb[3]=b0.w; bb[4]=b1.x; bb[5]=b1.y; bb[6]=b1.z; bb[7]=b1.w;
    } else {
      u32x4 gv = *(const u32x4*)((const u16*)g + c);
      u32x4 bv = *(const u32x4*)((const u16*)b + c);
      gg[0]=bf2f((u16)(gv.x&0xffff)); gg[1]=bf2f((u16)(gv.x>>16));
      gg[2]=bf2f((u16)(gv.y&0xffff)); gg[3]=bf2f((u16)(gv.y>>16));
      gg[4]=bf2f((u16)(gv.z&0xffff)); gg[5]=bf2f((u16)(gv.z>>16));
      gg[6]=bf2f((u16)(gv.w&0xffff)); gg[7]=bf2f((u16)(gv.w>>16));
      bb[0]=bf2f((u16)(bv.x&0xffff)); bb[1]=bf2f((u16)(bv.x>>16));
      bb[2]=bf2f((u16)(bv.y&0xffff)); bb[3]=bf2f((u16)(bv.y>>16));
      bb[4]=bf2f((u16)(bv.z&0xffff)); bb[5]=bf2f((u16)(bv.z>>16));
      bb[6]=bf2f((u16)(bv.w&0xffff)); bb[7]=bf2f((u16)(bv.w>>16));
    }
    float o_[8];
#pragma unroll
    for (int e2i = 0; e2i < 8; ++e2i) o_[e2i] = (e[e2i] - mean) * rstd * gg[e2i] + bb[e2i];
    if (of) {
      f32x4 o0 = {o_[0], o_[1], o_[2], o_[3]}, o1 = {o_[4], o_[5], o_[6], o_[7]};
      *(f32x4*)(of + c) = o0; *(f32x4*)(of + c + 4) = o1;
    } else {
      u32x4 q = { (u32)f2bf(o_[0]) | ((u32)f2bf(o_[1]) << 16),
                  (u32)f2bf(o_[2]) | ((u32)f2bf(o_[3]) << 16),
                  (u32)f2bf(o_[4]) | ((u32)f2bf(o_[5]) << 16),
                  (u32)f2bf(o_[6]) | ((u32)f2bf(o_[7]) << 16) };
      *(u32x4*)(ob + c) = q;
    }
  }
}

__global__ __launch_bounds__(256) void ln_rows(
    const u16* __restrict__ in, const void* __restrict__ g, const void* __restrict__ b,
    void* __restrict__ out, int N, const int* __restrict__ dtf, int isfinal)
{
  const int f = dtf[0];
  long row = blockIdx.x;
  const u16* ip = in + row * N;
  float* of = (isfinal && f) ? (float*)out + row * N : nullptr;
  u16*   ob = of ? nullptr : (u16*)out + row * N;
  ln_row(ip, g, b, ob, of, N, f);
}

// merged LN for q (1664x768), k (1028x768), mid (1028x6656)
__global__ __launch_bounds__(256) void mln3_k(
    u16* __restrict__ qb, const void* __restrict__ gq, const void* __restrict__ bq,
    u16* __restrict__ kb, const void* __restrict__ gk, const void* __restrict__ bk,
    u16* __restrict__ mb, const void* __restrict__ gv, const void* __restrict__ bv,
    const int* __restrict__ dtf)
{
  const int f = dtf[0];
  int row = blockIdx.x;
  u16* ip; const void *g, *b; int N;
  if (row < 1664)      { ip = qb + (long)row * 768; g = gq; b = bq; N = 768; }
  else if (row < 2692) { ip = kb + (long)(row - 1664) * 768; g = gk; b = bk; N = 768; }
  else                 { ip = mb + (long)(row - 2692) * 6656; g = gv; b = bv; N = 6656; }
  ln_row(ip, g, b, ip, nullptr, N, f);
}

// ------------------------------------------------------------- wbar ---------
// row means of Wconv (bf16 copy): r = g*64+l over 768 cols
__global__ __launch_bounds__(256) void wbar_k(const u16* __restrict__ Wb,
                                              float* __restrict__ wbar)
{
  int r = blockIdx.x * 4 + (threadIdx.x >> 6);
  int lane = threadIdx.x & 63;
  const u16* p = Wb + (long)r * 768;
  float s = 0.f;
  for (int c = lane; c < 768; c += 64) s += bf2f(p[c]);
#pragma unroll
  for (int o = 32; o; o >>= 1) s += __shfl_xor(s, o, 64);
  if (lane == 0) wbar[r] = s * (1.f / 768.f);
}

// ------------------------------------------------------------- stats2 -------
// single pass over all 1028 (b,j) rows; midi padded to 264 rows per (b,g)
__global__ __launch_bounds__(256) void stats2_k(
    const u16* __restrict__ midbf, const u16* __restrict__ Y, const float* __restrict__ wbar,
    u16* __restrict__ midi, float* __restrict__ pim)
{
  int g = blockIdx.y;
  int r = blockIdx.x * 4 + (threadIdx.x >> 6);   // 0..1027 (grid.x = 257)
  int lane = threadIdx.x & 63;
  int b = r / 257, j = r - b * 257;
  float m = bf2f(midbf[(long)r * 6656 + g * 64 + lane]);
  float y = bf2f(Y[((long)g * 1028 + r) * 64 + lane]);
  float wb = wbar[g * 64 + lane];
  float mup = m * wb, q2p = m * y;
#pragma unroll
  for (int o = 32; o; o >>= 1) { mup += __shfl_xor(mup, o, 64); q2p += __shfl_xor(q2p, o, 64); }
  float var = q2p - mup * mup;
  float inv = rsqrtf(fmaxf(var, 0.f) + 1e-5f);
  long zidx = (long)b * 104 + g;
  midi[(zidx * 264 + j) * 64 + lane] = f2bf(inv * m);
  if (lane == 0) pim[zidx * 257 + j] = inv * mup;
}

// ------------------------------------------------------------- softmax ------
__global__ __launch_bounds__(256) void softmax_k(
    const float* __restrict__ simf, const float* __restrict__ pim,
    u16* __restrict__ Abf, u16* __restrict__ A2bf, float* __restrict__ s_sh)
{
  int bh = blockIdx.x;
  int b = bh / 6, h = bh - b * 6;
  int tid = threadIdx.x, lane = tid & 63, wave = tid >> 6;
  int i = blockIdx.y * 4 + wave;
  int g = i % 104, rq = i / 104;
  const float* sp_ = simf + ((long)bh * 416 + i) * 257;
  float s[5];
#pragma unroll
  for (int jc = 0; jc < 5; ++jc) {
    int j = jc * 64 + lane;
    s[jc] = (j < 257) ? sp_[j] : -1e30f;
  }
  float mx = -1e30f;
#pragma unroll
  for (int jc = 0; jc < 5; ++jc) mx = fmaxf(mx, s[jc]);
#pragma unroll
  for (int o = 32; o; o >>= 1) mx = fmaxf(mx, __shfl_xor(mx, o, 64));
  float p[5], sum = 0.f, sp = 0.f;
  long pimb = ((long)b * 104 + g) * 257;
#pragma unroll
  for (int jc = 0; jc < 5; ++jc) {
    int j = jc * 64 + lane;
    float pv = 0.f;
    if (j < 257) { pv = __expf(s[jc] - mx); sp = fmaf(pv, pim[pimb + j], sp); }
    p[jc] = pv; sum += pv;
  }
#pragma unroll
  for (int o = 32; o; o >>= 1) { sum += __shfl_xor(sum, o, 64); sp += __shfl_xor(sp, o, 64); }
  float rs = 1.f / sum;
  long arow  = ((long)bh * 416 + i) * 264;
  long a2row = (((long)b * 104 + g) * 24 + h * 4 + rq) * 264;
#pragma unroll
  for (int jc = 0; jc < 5; ++jc) {
    int j = jc * 64 + lane;
    if (j < 257) { u16 pb = f2bf(p[jc] * rs); Abf[arow + j] = pb; A2bf[a2row + j] = pb; }
    else if (j < 264) { Abf[arow + j] = 0; A2bf[a2row + j] = 0; }
  }
  if (lane == 0) s_sh[(long)bh * 416 + i] = sp * rs;
}

// -------------------------------------------------- fused O-gemm + combine --
__global__ __launch_bounds__(256) void oc_k(
    const u16* __restrict__ T, const u16* __restrict__ Wb,
    const float* __restrict__ s_sh, const float* __restrict__ c_buf,
    const void* __restrict__ gv2, const void* __restrict__ bv2,
    u16* __restrict__ opbf, const int* __restrict__ dtf)
{
  const int f = dtf[0];
  int z = blockIdx.x;                 // b*104+g
  int b = z / 104, g = z - b * 104;
  int tid = threadIdx.x;
  __shared__ float Ts[24][64];        // 6 KB
  const u16* tp = T + (long)z * 1536;
  for (int idx = tid; idx < 1536; idx += 256) Ts[idx >> 6][idx & 63] = bf2f(tp[idx]);
  __syncthreads();
  const int dh = tid & 127;
  const int hbase = (tid >> 7) * 3;   // threads 0..127 -> h 0..2, 128..255 -> h 3..5
  const u16* wg = Wb + (long)g * 49152;
#pragma unroll
  for (int hh = 0; hh < 3; ++hh) {
    int h = hbase + hh;
    int d = h * 128 + dh;
    const u16* wp = wg + d;
    float a0 = 0.f, a1 = 0.f, a2 = 0.f, a3 = 0.f;
#pragma unroll 16
    for (int k = 0; k < 64; ++k) {
      float w = bf2f(wp[(long)k * 768]);
      a0 = fmaf(Ts[h * 4 + 0][k], w, a0);
      a1 = fmaf(Ts[h * 4 + 1][k], w, a1);
      a2 = fmaf(Ts[h * 4 + 2][k], w, a2);
      a3 = fmaf(Ts[h * 4 + 3][k], w, a3);
    }
    float acc[4] = {a0, a1, a2, a3};
    float gvd = gld(gv2, d, f), bvd = gld(bv2, d, f);
#pragma unroll
    for (int rq = 0; rq < 4; ++rq) {
      int i = rq * 104 + g;
      float ssh = s_sh[((long)b * 6 + h) * 416 + i];
      float val = gvd * (acc[rq] - ssh) + bvd
                + c_buf[(((long)b * 6 + h) * 416 + i) * 128 + dh];
      opbf[((long)b * 416 + i) * 768 + d] = f2bf(val);
    }
  }
}

// ---------------------------------------------------------------- host ------
static void launch_gemm(const void* A, const void* B, float* Cf, u16* Cb, int obf,
                        int M, int N, int K, int lda, int ldb, int ldc,
                        long sAo, long sAi, int adiv, long sBo, long sBi, int bdiv,
                        long sC, int zoff, int Z, int btrans, float alpha,
                        const int* dtf, int aSel, int bSel, hipStream_t st)
{
  dim3 grid((M + 63) / 64, (N + 63) / 64, Z);
  gemm_bf16<<<grid, dim3(256), 0, st>>>(A, B, Cf, Cb, obf, M, N, K, lda, ldb, ldc,
                                        sAo, sAi, adiv, sBo, sBi, bdiv,
                                        sC, zoff, btrans, alpha, dtf, aSel, bSel);
}

extern "C" void kernel_launch(void* const* d_in, const int* in_sizes, int n_in,
                              void* d_out, int out_size, void* d_ws, size_t ws_size,
                              hipStream_t stream)
{
  (void)in_sizes; (void)n_in;
  const void* x   = d_in[0];
  const void* ctx = d_in[1];
  const void* Wq  = d_in[2];
  const void* gq  = d_in[3];
  const void* bq  = d_in[4];
  const void* Wk  = d_in[5];
  const void* gk  = d_in[6];
  const void* bk  = d_in[7];
  const void* Wv  = d_in[8];
  const void* gv1 = d_in[9];
  const void* bv1 = d_in[10];
  const void* Wcv = d_in[11];
  const void* gv2 = d_in[12];
  const void* bv2 = d_in[13];
  const void* Wo  = d_in[14];
  const void* go  = d_in[15];
  const void* bo  = d_in[16];

  // -------- workspace layout --------
  const size_t SZ_FLAG = 256;
  const size_t SZ_QBF  = 2555904;
  const size_t SZ_KBF  = 1579008;
  const size_t SZ_MID  = 13684736;
  const size_t SZ_MM   = 1703936;
  const size_t SZ_WB   = 26624;
  const size_t SZ_MIDI = 14057472;   // 416 * 264 * 64 bf16 (264-row padded)
  const size_t SZ_PIM  = 427648;
  const size_t SZ_ABF  = 5271552;
  const size_t SZ_A2   = 5271552;
  const size_t SZ_SSH  = 39936;
  const size_t SZ_CB   = 1579008;
  const size_t SZ_WCVB = 10223616;   // 104*64*768 bf16
  const size_t SZ_YF   = 13684736;   // 104*1028*64 bf16
  const size_t SZ_WT   = 1179648;    // 768*768 bf16 (x3: WqT, WkT, WoT)
  const size_t SZ_WVT  = 10223616;   // 6656*768 bf16 (dedicated: live during mgemm3)
  const size_t SZ_CTXT = 1622016;    // 4*768*264 bf16 (ctx^T, zero-padded cols)
  const size_t REQUIRED = SZ_FLAG + SZ_QBF + SZ_KBF + SZ_MID + SZ_MM + SZ_WB +
                          SZ_MIDI + SZ_PIM + SZ_ABF + SZ_A2 + SZ_SSH + SZ_CB +
                          SZ_WCVB + SZ_YF + 3 * SZ_WT + SZ_WVT + SZ_CTXT;  // 85,490,560

  if (ws_size < REQUIRED) {
    fill_k<<<(out_size + 255) / 256, 256, 0, stream>>>((u16*)d_out, (float)(ws_size >> 20), out_size);
    return;
  }

  char* p = (char*)d_ws;
  int*   dtf   = (int*)  p;                 p += SZ_FLAG;
  u16*   qbf   = (u16*)  p;                 p += SZ_QBF;
  u16*   kbf   = (u16*)  p;                 p += SZ_KBF;
  char*  midrg = p;                         p += SZ_MID;
  char*  mmrg  = p;                         p += SZ_MM;
  float* wbar  = (float*)p;                 p += SZ_WB;
  u16*   midi  = (u16*)  p;                 p += SZ_MIDI;
  float* pim   = (float*)p;                 p += SZ_PIM;
  char*  abfrg = p;                         p += SZ_ABF;
  u16*   A2bf  = (u16*)  p;                 p += SZ_A2;
  float* s_sh  = (float*)p;                 p += SZ_SSH;
  u16*   cb    = (u16*)  p;                 p += SZ_CB;
  u16*   wcvb  = (u16*)  p;                 p += SZ_WCVB;
  u16*   yfull = (u16*)  p;                 p += SZ_YF;
  u16*   wqt2  = (u16*)  p;                 p += SZ_WT;
  u16*   wkt2  = (u16*)  p;                 p += SZ_WT;
  u16*   wot2  = (u16*)  p;                 p += SZ_WT;
  u16*   wvt   = (u16*)  p;                 p += SZ_WVT;
  u16*   ctxT  = (u16*)  p;                 p += SZ_CTXT;

  u16*   midbf = (u16*)midrg;
  float* simf  = (float*)midrg;
  float* c_buf = (float*)midrg;
  u16*   Tb16  = (u16*)(midrg + 5111808);
  u16*   Gb    = (u16*)mmrg;
  u16*   xb    = (u16*)abfrg;
  u16*   Abf   = (u16*)abfrg;
  u16*   opbf  = (u16*)abfrg;

  probe_k<<<1, 256, 0, stream>>>((const u32*)x, dtf);

  // ---- prep: bf16 copies (x, ctx, Wconv) + midi pad zeroing ----
  {
    const int n0_ = 1277952, n1_ = 789504, n2_ = 5111808, n3_ = 186368;  // all %8 == 0
    long tot = (long)n0_ + n1_ + n2_ + n3_;
    int blocks = (int)((tot / 8 + 255) / 256);
    convb4_k<<<blocks, 256, 0, stream>>>(x, xb, n0_, ctx, cb, n1_, Wcv, wcvb, n2_,
                                         midi, n3_, dtf);
  }
  // ---- merged transposes: Wq/Wk/Wo + Wv + ctx^T ----
  transM_k<<<7584, 256, 0, stream>>>(Wq, Wk, Wo, Wv, ctx,
                                     wqt2, wkt2, wot2, wvt, ctxT, dtf);

  // ---- q/k/mid GEMMs in one launch ----
  mgemm3_k<<<600, 256, 0, stream>>>(xb, wqt2, qbf, cb, wkt2, kbf, cb, wvt, midbf);
  // ---- q/k/mid LNs in one launch ----
  mln3_k<<<3720, 256, 0, stream>>>(qbf, gq, bq, kbf, gk, bk, midbf, gv1, bv1, dtf);

  // Gram: M[g] = Wconv[g] @ Wconv[g]^T / 768  (bf16 inputs -> fast staging path)
  launch_gemm(wcvb, wcvb, nullptr, Gb, 1, 64, 64, 768, 768, 768, 64,
              49152, 0, 1, 49152, 0, 1, 4096, 0, 104, 1, 1.f / 768.f, dtf, 0, 0, stream);
  wbar_k<<<1664, 256, 0, stream>>>(wcvb, wbar);
  // stats via MFMA: Y = mid_g @ M[g], single shot over all 1028 rows
  launch_gemm(midbf, Gb, nullptr, yfull, 1,
              1028, 64, 64, 6656, 64, 64,
              0, 64, 104, 4096, 0, 1, 65792, 0, 104, 1, 1.f, dtf, 0, 0, stream);
  stats2_k<<<dim3(257, 104), 256, 0, stream>>>(midbf, yfull, wbar, midi, pim);

  // sim = scale^2 * q @ k^T   (z = b*6+h, btrans, fp32 out; overwrites midbf region)
  launch_gemm(qbf, kbf, simf, nullptr, 0, 416, 257, 128, 768, 768, 257,
              319488, 128, 6, 197376, 128, 6, 106912, 0, 24, 1,
              0.08838834764831845f, dtf, 0, 0, stream);
  softmax_k<<<dim3(24, 104), 256, 0, stream>>>(simf, pim, Abf, A2bf, s_sh);

  // c = A @ ctx_head   (z = b*6+h; btrans fast path via ctx^T, K=264 all-vector)
  launch_gemm(Abf, ctxT, c_buf, nullptr, 0, 416, 128, 264, 264, 264, 128,
              109824, 0, 1, 202752, 33792, 6, 53248, 0, 24, 1, 1.f, dtf, 0, 0, stream);
  // T = A2 @ midi      (z = b*104+g; K=264, midi 264-row padded, pads zeroed)
  launch_gemm(A2bf, midi, nullptr, Tb16, 1, 24, 64, 264, 264, 64, 64,
              6336, 0, 1, 16896, 0, 1, 1536, 0, 416, 0, 1.f, dtf, 0, 0, stream);

  // fused O-gemm + combine: only the consumed head-diagonal slices computed
  oc_k<<<416, 256, 0, stream>>>(Tb16, wcvb, s_sh, c_buf, gv2, bv2, opbf, dtf);

  // out = LN(out_pre @ Wo): GEMM -> qbf scratch, LN -> d_out (flag dtype)
  {
    dim3 grid(13, 6, 1);
    gemm128<<<grid, dim3(256), 0, stream>>>(opbf, wot2, qbf, 1664, 768, 768, 768, 768, 768);
  }
  ln_rows<<<1664, 256, 0, stream>>>(qbf, go, bo, d_out, 768, dtf, 1);
}

// Round 4
// 273.233 us; speedup vs baseline: 1.4712x; 1.1313x over previous
//
#include <hip/hip_runtime.h>

// SubjBasisGenerator fused pipeline. B=4 NQ=416 NC=257 D=768 H=6 DH=128 G=104 R=4 LORA=64
// R14: dispatch count 16 -> 11. (1) prep_k = convb4+transM+wbar (wbar reads raw
//      Wcv to avoid intra-launch race). (2) mg4_k = mgemm3+Gram. (3) ysim_k =
//      Y-gemm + sim-gemm; simf de-aliased from midbf (dedicated 10.3MB buffer)
//      since Y reads midbf in the same launch. (4) ct_k = c-gemm + T-gemm.
//      (5) gemm64_body stripped of dead fp32-input paths (all callers bf16).
//      Bodies byte-equivalent to R13; only launch plumbing changed.
// R13/R12: merged q/k/mid gemm128s (B-panel-major), merged LNs/transposes,
//      ctx^T btrans fast path, K padded 257->264, 264-row-padded midi.
// R11: oc_k fusion (O-gemm+combine), Wconv bf16 pre-convert, Y de-chunked.
// R10: gemm128 — 128x128 tile, 4x4 MFMA acc/wave, global_load_lds width-16.
//
// Algebra: the grouped-conv+LN v-path decomposes exactly (no (B,G,NC,768) tensor):
//   sum_j A_j v_j = gv2*( (sum_j A_j inv_j mid_j)@Wconv[g] - sum_j A_j inv_j mu_j )
//                   + bv2 + (A @ ctx)
//   q2[b,g,j] = mid^T M[g] mid = mid . (M[g] @ mid),  M[g] = Wconv[g]Wconv[g]^T/768

typedef unsigned short u16;
typedef unsigned int   u32;
typedef __attribute__((ext_vector_type(4))) float f32x4;
typedef __attribute__((ext_vector_type(4))) u32   u32x4;
typedef __attribute__((ext_vector_type(8))) short bf16x8;

__device__ __forceinline__ float bf2f(u16 v) { return __uint_as_float(((u32)v) << 16); }
__device__ __forceinline__ u16 f2bf(float f) {
  u32 u = __float_as_uint(f);
  u32 r = u + 0x7fffu + ((u >> 16) & 1u);  // RNE
  return (u16)(r >> 16);
}
__device__ __forceinline__ float gld(const void* p, long idx, int f32) {
  return f32 ? ((const float*)p)[idx] : bf2f(((const u16*)p)[idx]);
}

typedef const __attribute__((address_space(1))) u32 gas_u32;
typedef __attribute__((address_space(3))) u32 las_u32;

// async 16B/lane global->LDS; LDS dest = wave-uniform base + lane*16 (m97).
__device__ __forceinline__ void stage16(const u16* g, u16* lbase, int lane) {
#if __has_builtin(__builtin_amdgcn_global_load_lds)
  (void)lane;
  __builtin_amdgcn_global_load_lds((gas_u32*)g, (las_u32*)lbase, 16, 0, 0);
#else
  *(u32x4*)(lbase + lane * 8) = *(const u32x4*)g;
#endif
}

// ------------------------------------------------------------ dtype probe ---
__global__ __launch_bounds__(256) void probe_k(const u32* __restrict__ xw, int* __restrict__ flag) {
  int tid = threadIdx.x, c = 0;
  for (int i = tid; i < 4096; i += 256) {
    u16 lo = (u16)(xw[i] & 0xffffu);
    float a = fabsf(bf2f(lo));
    if (lo == 0 || (a >= 1e-3f && a <= 32.f)) ++c;
  }
#pragma unroll
  for (int o = 32; o; o >>= 1) c += __shfl_xor(c, o, 64);
  __shared__ int r[4];
  if ((tid & 63) == 0) r[tid >> 6] = c;
  __syncthreads();
  if (tid == 0) flag[0] = (r[0] + r[1] + r[2] + r[3] >= 2048) ? 0 : 1;  // 1 = fp32
}

// ------------------------------------------------------------ diag fill -----
__global__ __launch_bounds__(256) void fill_k(u16* p, float v, int n) {
  int i = blockIdx.x * 256 + threadIdx.x;
  if (i < n) p[i] = f2bf(v);
}

// --------------------------------------------------------------- prep_k -----
// blocks [0,3597): ext->bf16 copies (x, ctx, Wconv) + midi pad-row zeroing
// blocks [3597,11181): transposes Wq/Wk/Wo (768^2), Wv (768x6656), ctx^T
// blocks [11181,12845): wbar row means (reads RAW Wcv — no intra-launch dep)
__global__ __launch_bounds__(256) void prep_k(
    const void* __restrict__ x,   u16* __restrict__ xb,
    const void* __restrict__ ctx, u16* __restrict__ cbuf,
    const void* __restrict__ Wcv, u16* __restrict__ wcvb,
    u16* __restrict__ midi,
    const void* __restrict__ Wq, const void* __restrict__ Wk,
    const void* __restrict__ Wo, const void* __restrict__ Wv,
    u16* __restrict__ wqt, u16* __restrict__ wkt, u16* __restrict__ wot,
    u16* __restrict__ wvt, u16* __restrict__ ctxT,
    float* __restrict__ wbar, const int* __restrict__ dtf)
{
  const int f = dtf[0];
  int bid = blockIdx.x;
  __shared__ float s[32][33];
  if (bid < 3597) {
    // ---- convb4 ----
    const long n0_ = 1277952, n1_ = 789504, n2_ = 5111808, n3_ = 186368;
    long i = ((long)bid * 256 + threadIdx.x) * 8;
    const long t0 = n0_, t1 = t0 + n1_, t2 = t1 + n2_, t3 = t2 + n3_;
    if (i >= t3) return;
    if (i >= t2) {
      long e = i - t2;                 // zero 7 pad rows per midi z-block
      long z = e / 448, off = e - z * 448;
      u32x4 zz = {0u, 0u, 0u, 0u};
      *(u32x4*)(midi + z * 16896 + 16448 + off) = zz;
      return;
    }
    const void* in; u16* out;
    if (i < t0)      { in = x;    out = xb; }
    else if (i < t1) { in = ctx;  out = cbuf; i -= t0; }
    else             { in = Wcv;  out = wcvb; i -= t1; }
    if (f) {
      const float* ip = (const float*)in + i;
      f32x4 a = *(const f32x4*)ip, b = *(const f32x4*)(ip + 4);
      u32x4 q = { (u32)f2bf(a.x) | ((u32)f2bf(a.y) << 16),
                  (u32)f2bf(a.z) | ((u32)f2bf(a.w) << 16),
                  (u32)f2bf(b.x) | ((u32)f2bf(b.y) << 16),
                  (u32)f2bf(b.z) | ((u32)f2bf(b.w) << 16) };
      *(u32x4*)(out + i) = q;
    } else {
      *(u32x4*)(out + i) = *(const u32x4*)((const u16*)in + i);
    }
  } else if (bid < 11181) {
    // ---- transM ----
    int t = bid - 3597;
    const void* in; u16* out;
    int inK, inN, ldo, outK, nx;
    long inBase = 0, outBase = 0;
    if (t < 1728) {                    // 3 x 768x768 weights: 576 tiles each
      int w = t / 576; t -= w * 576;
      in  = w == 0 ? Wq : w == 1 ? Wk : Wo;
      out = w == 0 ? wqt : w == 1 ? wkt : wot;
      inK = 768; inN = 768; ldo = 768; outK = 768; nx = 24;
    } else if (t < 6720) {             // Wv 768x6656: 208 n-tiles x 24 k-tiles
      t -= 1728;
      in = Wv; out = wvt;
      inK = 768; inN = 6656; ldo = 768; outK = 768; nx = 208;
    } else {                           // ctxT: 4 b x (24 n-tiles x 9 k-tiles)
      t -= 6720;
      int b = t / 216; t -= b * 216;
      in = ctx; out = ctxT;
      inK = 257; inN = 768; ldo = 264; outK = 264; nx = 24;
      inBase = (long)b * 257 * 768; outBase = (long)b * 768 * 264;
    }
    int n0 = (t % nx) * 32, k0 = (t / nx) * 32;
    int tx = threadIdx.x & 31, ty = threadIdx.x >> 5;  // 32 x 8
#pragma unroll
    for (int i = 0; i < 32; i += 8) {
      int k = k0 + ty + i, n = n0 + tx;
      float v = 0.f;
      if (k < inK && n < inN) v = gld(in, inBase + (long)k * inN + n, f);
      s[ty + i][tx] = v;
    }
    __syncthreads();
#pragma unroll
    for (int i = 0; i < 32; i += 8) {
      int n = n0 + ty + i, k = k0 + tx;
      if (n < inN && k < outK) out[outBase + (long)n * ldo + k] = f2bf(s[tx][ty + i]);
    }
  } else {
    // ---- wbar: row means of raw Wconv, r = g*64+l over 768 cols ----
    int r = (bid - 11181) * 4 + (threadIdx.x >> 6);
    int lane = threadIdx.x & 63;
    long base = (long)r * 768;
    float sm = 0.f;
    for (int c = lane; c < 768; c += 64) sm += gld(Wcv, base + c, f);
#pragma unroll
    for (int o = 32; o; o >>= 1) sm += __shfl_xor(sm, o, 64);
    if (lane == 0) wbar[r] = sm * (1.f / 768.f);
  }
}

// ------------------------------------------------------------- gemm128 ------
// C_bf16 = A_bf16[M,K] @ B_bf16[N,K]^T. Requires N%128==0, K%32==0; M-tail via
// row-clamped staging + guarded writes. 128x128 tile, BK=32, 4 waves each 64x64.
__device__ __forceinline__ void gemm128_body(
    const u16* __restrict__ A, const u16* __restrict__ B, u16* __restrict__ C,
    int M, int N, int K, int lda, int ldb, int ldc, int m0, int n0)
{
  __shared__ __attribute__((aligned(16))) u16 As[128 * 32];
  __shared__ __attribute__((aligned(16))) u16 Bs[128 * 32];
  const int tid = threadIdx.x, lane = tid & 63, wave = tid >> 6;
  const int wm = (wave >> 1) * 64, wn = (wave & 1) * 64;
  const int fm = lane & 15, fq = lane >> 4;

  const int srow = lane >> 2, selem = (lane & 3) * 8;
  int ra1 = m0 + wave * 16 + srow;      if (ra1 > M - 1) ra1 = M - 1;
  int ra2 = m0 + 64 + wave * 16 + srow; if (ra2 > M - 1) ra2 = M - 1;
  const int rb1 = n0 + wave * 16 + srow;
  const int rb2 = n0 + 64 + wave * 16 + srow;
  const u16* pa1 = A + (long)ra1 * lda + selem;
  const u16* pa2 = A + (long)ra2 * lda + selem;
  const u16* pb1 = B + (long)rb1 * ldb + selem;
  const u16* pb2 = B + (long)rb2 * ldb + selem;
  u16* la1 = As + wave * 512;
  u16* la2 = As + 2048 + wave * 512;
  u16* lb1 = Bs + wave * 512;
  u16* lb2 = Bs + 2048 + wave * 512;

  f32x4 acc[4][4];
  const f32x4 zero4 = {0.f, 0.f, 0.f, 0.f};
#pragma unroll
  for (int a_ = 0; a_ < 4; ++a_)
#pragma unroll
    for (int b_ = 0; b_ < 4; ++b_) acc[a_][b_] = zero4;

  for (int k0 = 0; k0 < K; k0 += 32) {
    stage16(pa1, la1, lane);
    stage16(pa2, la2, lane);
    stage16(pb1, lb1, lane);
    stage16(pb2, lb2, lane);
    pa1 += 32; pa2 += 32; pb1 += 32; pb2 += 32;
    __syncthreads();
    bf16x8 fa[4], fb[4];
#pragma unroll
    for (int mt = 0; mt < 4; ++mt)
      fa[mt] = *(const bf16x8*)&As[(wm + mt * 16 + fm) * 32 + fq * 8];
#pragma unroll
    for (int nt = 0; nt < 4; ++nt)
      fb[nt] = *(const bf16x8*)&Bs[(wn + nt * 16 + fm) * 32 + fq * 8];
#pragma unroll
    for (int mt = 0; mt < 4; ++mt)
#pragma unroll
      for (int nt = 0; nt < 4; ++nt)
        acc[mt][nt] = __builtin_amdgcn_mfma_f32_16x16x32_bf16(fa[mt], fb[nt], acc[mt][nt], 0, 0, 0);
    __syncthreads();
  }
#pragma unroll
  for (int mt = 0; mt < 4; ++mt)
#pragma unroll
    for (int nt = 0; nt < 4; ++nt)
#pragma unroll
      for (int rr = 0; rr < 4; ++rr) {
        int gm = m0 + wm + mt * 16 + fq * 4 + rr;
        int gn = n0 + wn + nt * 16 + fm;
        if (gm < M) C[(long)gm * ldc + gn] = f2bf(acc[mt][nt][rr]);
      }
}

__global__ __launch_bounds__(256) void gemm128(
    const u16* __restrict__ A, const u16* __restrict__ B, u16* __restrict__ C,
    int M, int N, int K, int lda, int ldb, int ldc)
{
  gemm128_body(A, B, C, M, N, K, lda, ldb, ldc, blockIdx.x * 128, blockIdx.y * 128);
}

// ------------------------------------------------- gemm64 body (all-bf16) ---
// 64x64 tile, BK=32, 2x2 acc/wave. Pointers pre-offset by caller (batch z).
#define LDS_S 40

__device__ __forceinline__ void gemm64_body(
    u16* As, u16* Bs,
    const u16* __restrict__ A16, const u16* __restrict__ B16,
    float* Cf, u16* Cb,
    int M, int N, int K, int lda, int ldb, int ldc,
    int btrans, float alpha, int m0, int n0)
{
  const int tid = threadIdx.x;
  const int lane = tid & 63, wave = tid >> 6;
  const int wm = (wave >> 1) * 32, wn = (wave & 1) * 32;
  const int fm = lane & 15, fq = lane >> 4;
  const int ar = tid >> 2, ak = (tid & 3) * 8;
  const int bk = tid >> 3, bn = (tid & 7) * 8;

  f32x4 acc[2][2];
  const f32x4 zero4 = {0.f, 0.f, 0.f, 0.f};
#pragma unroll
  for (int a_ = 0; a_ < 2; ++a_)
#pragma unroll
    for (int b_ = 0; b_ < 2; ++b_) acc[a_][b_] = zero4;

  for (int k0 = 0; k0 < K; k0 += 32) {
    {
      int gm = m0 + ar, gk = k0 + ak;
      long idx = (long)gm * lda + gk;
      if (gm < M && gk + 8 <= K) {
        *(u32x4*)&As[ar * LDS_S + ak] = *(const u32x4*)(A16 + idx);
      } else {
#pragma unroll
        for (int e = 0; e < 8; ++e)
          As[ar * LDS_S + ak + e] = (gm < M && gk + e < K) ? A16[idx + e] : (u16)0;
      }
    }
    if (btrans) {
      int gn = n0 + ar, gk = k0 + ak;
      long idx = (long)gn * ldb + gk;
      if (gn < N && gk + 8 <= K) {
        *(u32x4*)&Bs[ar * LDS_S + ak] = *(const u32x4*)(B16 + idx);
      } else {
#pragma unroll
        for (int e = 0; e < 8; ++e)
          Bs[ar * LDS_S + ak + e] = (gn < N && gk + e < K) ? B16[idx + e] : (u16)0;
      }
    } else {
      int gk = k0 + bk;
      long idx = (long)gk * ldb + n0 + bn;
      u16 tmp[8];
      if (gk < K) {
        u32x4 v = *(const u32x4*)(B16 + idx);
        tmp[0] = (u16)(v.x & 0xffff); tmp[1] = (u16)(v.x >> 16);
        tmp[2] = (u16)(v.y & 0xffff); tmp[3] = (u16)(v.y >> 16);
        tmp[4] = (u16)(v.z & 0xffff); tmp[5] = (u16)(v.z >> 16);
        tmp[6] = (u16)(v.w & 0xffff); tmp[7] = (u16)(v.w >> 16);
      } else {
#pragma unroll
        for (int e = 0; e < 8; ++e) tmp[e] = 0;
      }
      int rot = tid & 7;  // spread LDS bank writes
#pragma unroll
      for (int e = 0; e < 8; ++e) {
        int ee = (e + rot) & 7;
        Bs[(bn + ee) * LDS_S + bk] = tmp[ee];
      }
    }
    __syncthreads();
    {
      bf16x8 fa[2], fb[2];
      fa[0] = *(const bf16x8*)&As[(wm +      fm) * LDS_S + fq * 8];
      fa[1] = *(const bf16x8*)&As[(wm + 16 + fm) * LDS_S + fq * 8];
      fb[0] = *(const bf16x8*)&Bs[(wn +      fm) * LDS_S + fq * 8];
      fb[1] = *(const bf16x8*)&Bs[(wn + 16 + fm) * LDS_S + fq * 8];
#pragma unroll
      for (int mt = 0; mt < 2; ++mt)
#pragma unroll
        for (int nt = 0; nt < 2; ++nt)
          acc[mt][nt] = __builtin_amdgcn_mfma_f32_16x16x32_bf16(fa[mt], fb[nt], acc[mt][nt], 0, 0, 0);
    }
    __syncthreads();
  }
#pragma unroll
  for (int mt = 0; mt < 2; ++mt)
#pragma unroll
    for (int nt = 0; nt < 2; ++nt)
#pragma unroll
      for (int rr = 0; rr < 4; ++rr) {
        int gm = m0 + wm + mt * 16 + fq * 4 + rr;
        int gn = n0 + wn + nt * 16 + fm;
        if (gm < M && gn < N) {
          float v = alpha * acc[mt][nt][rr];
          if (Cb) Cb[(long)gm * ldc + gn] = f2bf(v);
          else    Cf[(long)gm * ldc + gn] = v;
        }
      }
}

// -------------------------------------- mg4: q/k/mid gemm128s + Gram gemm ---
__global__ __launch_bounds__(256) void mg4_k(
    const u16* __restrict__ xb, const u16* __restrict__ wqt, u16* __restrict__ qbf,
    const u16* __restrict__ cbuf, const u16* __restrict__ wkt, u16* __restrict__ kbf,
    const u16* __restrict__ wvt, u16* __restrict__ midbf,
    const u16* __restrict__ wcvb, u16* __restrict__ Gb)
{
  int bid = blockIdx.x;
  if (bid < 600) {
    const u16 *A, *B; u16* C; int M, N, lid, mx;
    if (bid < 78)       { A = xb;   B = wqt; C = qbf;   M = 1664; N = 768;  lid = bid;       mx = 13; }
    else if (bid < 132) { A = cbuf; B = wkt; C = kbf;   M = 1028; N = 768;  lid = bid - 78;  mx = 9;  }
    else                { A = cbuf; B = wvt; C = midbf; M = 1028; N = 6656; lid = bid - 132; mx = 9;  }
    int m0 = (lid % mx) * 128, n0 = (lid / mx) * 128;
    gemm128_body(A, B, C, M, N, 768, 768, 768, N, m0, n0);
  } else {
    __shared__ __attribute__((aligned(16))) u16 As[64 * LDS_S];
    __shared__ __attribute__((aligned(16))) u16 Bs[64 * LDS_S];
    int z = bid - 600;   // 0..103: M[g] = Wconv_b[g] @ Wconv_b[g]^T / 768
    gemm64_body(As, Bs, wcvb + (long)z * 49152, wcvb + (long)z * 49152,
                nullptr, Gb + (long)z * 4096,
                64, 64, 768, 768, 768, 64, 1, 1.f / 768.f, 0, 0);
  }
}

// ------------------------------------------------ ysim: Y-gemm + sim-gemm ---
__global__ __launch_bounds__(256) void ysim_k(
    const u16* __restrict__ midbf, const u16* __restrict__ Gb, u16* __restrict__ yfull,
    const u16* __restrict__ qbf, const u16* __restrict__ kbf, float* __restrict__ simf)
{
  __shared__ __attribute__((aligned(16))) u16 As[64 * LDS_S];
  __shared__ __attribute__((aligned(16))) u16 Bs[64 * LDS_S];
  int bid = blockIdx.x;
  const u16 *A, *B; float* Cf = nullptr; u16* Cb = nullptr;
  int M, N, K, lda, ldb, ldc, btrans, m0, n0; float alpha;
  if (bid < 1768) {
    // Y = mid_g[1028x64] @ M[g][64x64]^T(sym);  z = g (m-fastest within g)
    int z = bid / 17, bx = bid % 17;
    A = midbf + (long)z * 64;  B = Gb + (long)z * 4096;  Cb = yfull + (long)z * 65792;
    M = 1028; N = 64; K = 64; lda = 6656; ldb = 64; ldc = 64;
    btrans = 1; alpha = 1.f; m0 = bx * 64; n0 = 0;
  } else {
    // sim = scale^2 * q @ k^T;  z = b*6+h
    int lid = bid - 1768; int z = lid / 35, r = lid % 35, bx = r % 7, by = r / 7;
    A = qbf + (long)(z / 6) * 319488 + (long)(z % 6) * 128;
    B = kbf + (long)(z / 6) * 197376 + (long)(z % 6) * 128;
    Cf = simf + (long)z * 106912;
    M = 416; N = 257; K = 128; lda = 768; ldb = 768; ldc = 257;
    btrans = 1; alpha = 0.08838834764831845f; m0 = bx * 64; n0 = by * 64;
  }
  gemm64_body(As, Bs, A, B, Cf, Cb, M, N, K, lda, ldb, ldc, btrans, alpha, m0, n0);
}

// --------------------------------------------------- ct: c-gemm + T-gemm ----
__global__ __launch_bounds__(256) void ct_k(
    const u16* __restrict__ Abf, const u16* __restrict__ ctxT, float* __restrict__ c_buf,
    const u16* __restrict__ A2bf, const u16* __restrict__ midi, u16* __restrict__ Tb16)
{
  __shared__ __attribute__((aligned(16))) u16 As[64 * LDS_S];
  __shared__ __attribute__((aligned(16))) u16 Bs[64 * LDS_S];
  int bid = blockIdx.x;
  const u16 *A, *B; float* Cf = nullptr; u16* Cb = nullptr;
  int M, N, K, lda, ldb, ldc, btrans, m0, n0; float alpha;
  if (bid < 336) {
    // c = A @ ctx_head (btrans via ctx^T, K=264); z = b*6+h
    int z = bid / 14, r = bid % 14, bx = r % 7, by = r / 7;
    A = Abf + (long)z * 109824;
    B = ctxT + (long)(z / 6) * 202752 + (long)(z % 6) * 33792;
    Cf = c_buf + (long)z * 53248;
    M = 416; N = 128; K = 264; lda = 264; ldb = 264; ldc = 128;
    btrans = 1; alpha = 1.f; m0 = bx * 64; n0 = by * 64;
  } else {
    // T = A2 @ midi (non-trans, K=264, 264-row-padded midi); z = b*104+g
    int z = bid - 336;
    A = A2bf + (long)z * 6336;
    B = midi + (long)z * 16896;
    Cb = Tb16 + (long)z * 1536;
    M = 24; N = 64; K = 264; lda = 264; ldb = 64; ldc = 64;
    btrans = 0; alpha = 1.f; m0 = 0; n0 = 0;
  }
  gemm64_body(As, Bs, A, B, Cf, Cb, M, N, K, lda, ldb, ldc, btrans, alpha, m0, n0);
}

// ------------------------------------------------------------- row LN -------
__device__ __forceinline__ void ln_row(
    const u16* __restrict__ ip, const void* __restrict__ g, const void* __restrict__ b,
    u16* __restrict__ ob, float* __restrict__ of, int N, int f)
{
  int tid = threadIdx.x, lane = tid & 63, wave = tid >> 6;
  const int nv = N >> 3;
  float s1 = 0.f, s2 = 0.f;
  for (int c8 = tid; c8 < nv; c8 += 256) {
    u32x4 v = *(const u32x4*)(ip + c8 * 8);
    float e0 = bf2f((u16)(v.x & 0xffff)), e1 = bf2f((u16)(v.x >> 16));
    float e2 = bf2f((u16)(v.y & 0xffff)), e3 = bf2f((u16)(v.y >> 16));
    float e4 = bf2f((u16)(v.z & 0xffff)), e5 = bf2f((u16)(v.z >> 16));
    float e6 = bf2f((u16)(v.w & 0xffff)), e7 = bf2f((u16)(v.w >> 16));
    s1 += ((e0 + e1) + (e2 + e3)) + ((e4 + e5) + (e6 + e7));
    s2 += ((e0*e0 + e1*e1) + (e2*e2 + e3*e3)) + ((e4*e4 + e5*e5) + (e6*e6 + e7*e7));
  }
#pragma unroll
  for (int o = 32; o; o >>= 1) { s1 += __shfl_xor(s1, o, 64); s2 += __shfl_xor(s2, o, 64); }
  __shared__ float red[8];
  if (lane == 0) { red[wave] = s1; red[4 + wave] = s2; }
  __syncthreads();
  s1 = red[0] + red[1] + red[2] + red[3];
  s2 = red[4] + red[5] + red[6] + red[7];
  float mean = s1 / N;
  float var = s2 / N - mean * mean;
  float rstd = rsqrtf(fmaxf(var, 0.f) + 1e-5f);
  for (int c8 = tid; c8 < nv; c8 += 256) {
    int c = c8 * 8;
    u32x4 v = *(const u32x4*)(ip + c);
    float e[8];
    e[0] = bf2f((u16)(v.x & 0xffff)); e[1] = bf2f((u16)(v.x >> 16));
    e[2] = bf2f((u16)(v.y & 0xffff)); e[3] = bf2f((u16)(v.y >> 16));
    e[4] = bf2f((u16)(v.z & 0xffff)); e[5] = bf2f((u16)(v.z >> 16));
    e[6] = bf2f((u16)(v.w & 0xffff)); e[7] = bf2f((u16)(v.w >> 16));
    float gg[8], bb[8];
    if (f) {
      const float* gp = (const float*)g + c; const float* bp = (const float*)b + c;
      f32x4 g0 = *(const f32x4*)gp, g1 = *(const f32x4*)(gp + 4);
      f32x4 b0 = *(const f32x4*)bp, b1 = *(const f32x4*)(bp + 4);
      gg[0]=g0.x; gg[1]=g0.y; gg[2]=g0.z; gg[3]=g0.w; gg[4]=g1.x; gg[5]=g1.y; gg[6]=g1.z; gg[7]=g1.w;
      bb[0]=b0.x; bb[1]=b0.y; bb[2]=b0.z; bb[3]=b0.w; bb[4]=b1.x; bb[5]=b1.y; bb[6]=b1.z; bb[7]=b1.w;
    } else {
      u32x4 gv = *(const u32x4*)((const u16*)g + c);
      u32x4 bv = *(const u32x4*)((const u16*)b + c);
      gg[0]=bf2f((u16)(gv.x&0xffff)); gg[1]=bf2f((u16)(gv.x>>16));
      gg[2]=bf2f((u16)(gv.y&0xffff)); gg[3]=bf2f((u16)(gv.y>>16));
      gg[4]=bf2f((u16)(gv.z&0xffff)); gg[5]=bf2f((u16)(gv.z>>16));
      gg[6]=bf2f((u16)(gv.w&0xffff)); gg[7]=bf2f((u16)(gv.w>>16));
      bb[0]=bf2f((u16)(bv.x&0xffff)); bb[1]=bf2f((u16)(bv.x>>16));
      bb[2]=bf2f((u16)(bv.y&0xffff)); bb[3]=bf2f((u16)(bv.y>>16));
      bb[4]=bf2f((u16)(bv.z&0xffff)); bb[5]=bf2f((u16)(bv.z>>16));
      bb[6]=bf2f((u16)(bv.w&0xffff)); bb[7]=bf2f((u16)(bv.w>>16));
    }
    float o_[8];
#pragma unroll
    for (int e2i = 0; e2i < 8; ++e2i) o_[e2i] = (e[e2i] - mean) * rstd * gg[e2i] + bb[e2i];
    if (of) {
      f32x4 o0 = {o_[0], o_[1], o_[2], o_[3]}, o1 = {o_[4], o_[5], o_[6], o_[7]};
      *(f32x4*)(of + c) = o0; *(f32x4*)(of + c + 4) = o1;
    } else {
      u32x4 q = { (u32)f2bf(o_[0]) | ((u32)f2bf(o_[1]) << 16),
                  (u32)f2bf(o_[2]) | ((u32)f2bf(o_[3]) << 16),
                  (u32)f2bf(o_[4]) | ((u32)f2bf(o_[5]) << 16),
                  (u32)f2bf(o_[6]) | ((u32)f2bf(o_[7]) << 16) };
      *(u32x4*)(ob + c) = q;
    }
  }
}

__global__ __launch_bounds__(256) void ln_rows(
    const u16* __restrict__ in, const void* __restrict__ g, const void* __restrict__ b,
    void* __restrict__ out, int N, const int* __restrict__ dtf, int isfinal)
{
  const int f = dtf[0];
  long row = blockIdx.x;
  const u16* ip = in + row * N;
  float* of = (isfinal && f) ? (float*)out + row * N : nullptr;
  u16*   ob = of ? nullptr : (u16*)out + row * N;
  ln_row(ip, g, b, ob, of, N, f);
}

// merged LN for q (1664x768), k (1028x768), mid (1028x6656)
__global__ __launch_bounds__(256) void mln3_k(
    u16* __restrict__ qb, const void* __restrict__ gq, const void* __restrict__ bq,
    u16* __restrict__ kb, const void* __restrict__ gk, const void* __restrict__ bk,
    u16* __restrict__ mb, const void* __restrict__ gv, const void* __restrict__ bv,
    const int* __restrict__ dtf)
{
  const int f = dtf[0];
  int row = blockIdx.x;
  u16* ip; const void *g, *b; int N;
  if (row < 1664)      { ip = qb + (long)row * 768; g = gq; b = bq; N = 768; }
  else if (row < 2692) { ip = kb + (long)(row - 1664) * 768; g = gk; b = bk; N = 768; }
  else                 { ip = mb + (long)(row - 2692) * 6656; g = gv; b = bv; N = 6656; }
  ln_row(ip, g, b, ip, nullptr, N, f);
}

// ------------------------------------------------------------- stats2 -------
// single pass over all 1028 (b,j) rows; midi padded to 264 rows per (b,g)
__global__ __launch_bounds__(256) void stats2_k(
    const u16* __restrict__ midbf, const u16* __restrict__ Y, const float* __restrict__ wbar,
    u16* __restrict__ midi, float* __restrict__ pim)
{
  int g = blockIdx.y;
  int r = blockIdx.x * 4 + (threadIdx.x >> 6);   // 0..1027 (grid.x = 257)
  int lane = threadIdx.x & 63;
  int b = r / 257, j = r - b * 257;
  float m = bf2f(midbf[(long)r * 6656 + g * 64 + lane]);
  float y = bf2f(Y[((long)g * 1028 + r) * 64 + lane]);
  float wb = wbar[g * 64 + lane];
  float mup = m * wb, q2p = m * y;
#pragma unroll
  for (int o = 32; o; o >>= 1) { mup += __shfl_xor(mup, o, 64); q2p += __shfl_xor(q2p, o, 64); }
  float var = q2p - mup * mup;
  float inv = rsqrtf(fmaxf(var, 0.f) + 1e-5f);
  long zidx = (long)b * 104 + g;
  midi[(zidx * 264 + j) * 64 + lane] = f2bf(inv * m);
  if (lane == 0) pim[zidx * 257 + j] = inv * mup;
}

// ------------------------------------------------------------- softmax ------
__global__ __launch_bounds__(256) void softmax_k(
    const float* __restrict__ simf, const float* __restrict__ pim,
    u16* __restrict__ Abf, u16* __restrict__ A2bf, float* __restrict__ s_sh)
{
  int bh = blockIdx.x;
  int b = bh / 6, h = bh - b * 6;
  int tid = threadIdx.x, lane = tid & 63, wave = tid >> 6;
  int i = blockIdx.y * 4 + wave;
  int g = i % 104, rq = i / 104;
  const float* sp_ = simf + ((long)bh * 416 + i) * 257;
  float s[5];
#pragma unroll
  for (int jc = 0; jc < 5; ++jc) {
    int j = jc * 64 + lane;
    s[jc] = (j < 257) ? sp_[j] : -1e30f;
  }
  float mx = -1e30f;
#pragma unroll
  for (int jc = 0; jc < 5; ++jc) mx = fmaxf(mx, s[jc]);
#pragma unroll
  for (int o = 32; o; o >>= 1) mx = fmaxf(mx, __shfl_xor(mx, o, 64));
  float p[5], sum = 0.f, sp = 0.f;
  long pimb = ((long)b * 104 + g) * 257;
#pragma unroll
  for (int jc = 0; jc < 5; ++jc) {
    int j = jc * 64 + lane;
    float pv = 0.f;
    if (j < 257) { pv = __expf(s[jc] - mx); sp = fmaf(pv, pim[pimb + j], sp); }
    p[jc] = pv; sum += pv;
  }
#pragma unroll
  for (int o = 32; o; o >>= 1) { sum += __shfl_xor(sum, o, 64); sp += __shfl_xor(sp, o, 64); }
  float rs = 1.f / sum;
  long arow  = ((long)bh * 416 + i) * 264;
  long a2row = (((long)b * 104 + g) * 24 + h * 4 + rq) * 264;
#pragma unroll
  for (int jc = 0; jc < 5; ++jc) {
    int j = jc * 64 + lane;
    if (j < 257) { u16 pb = f2bf(p[jc] * rs); Abf[arow + j] = pb; A2bf[a2row + j] = pb; }
    else if (j < 264) { Abf[arow + j] = 0; A2bf[a2row + j] = 0; }
  }
  if (lane == 0) s_sh[(long)bh * 416 + i] = sp * rs;
}

// -------------------------------------------------- fused O-gemm + combine --
__global__ __launch_bounds__(256) void oc_k(
    const u16* __restrict__ T, const u16* __restrict__ Wb,
    const float* __restrict__ s_sh, const float* __restrict__ c_buf,
    const void* __restrict__ gv2, const void* __restrict__ bv2,
    u16* __restrict__ opbf, const int* __restrict__ dtf)
{
  const int f = dtf[0];
  int z = blockIdx.x;                 // b*104+g
  int b = z / 104, g = z - b * 104;
  int tid = threadIdx.x;
  __shared__ float Ts[24][64];        // 6 KB
  const u16* tp = T + (long)z * 1536;
  for (int idx = tid; idx < 1536; idx += 256) Ts[idx >> 6][idx & 63] = bf2f(tp[idx]);
  __syncthreads();
  const int dh = tid & 127;
  const int hbase = (tid >> 7) * 3;   // threads 0..127 -> h 0..2, 128..255 -> h 3..5
  const u16* wg = Wb + (long)g * 49152;
#pragma unroll
  for (int hh = 0; hh < 3; ++hh) {
    int h = hbase + hh;
    int d = h * 128 + dh;
    const u16* wp = wg + d;
    float a0 = 0.f, a1 = 0.f, a2 = 0.f, a3 = 0.f;
#pragma unroll 16
    for (int k = 0; k < 64; ++k) {
      float w = bf2f(wp[(long)k * 768]);
      a0 = fmaf(Ts[h * 4 + 0][k], w, a0);
      a1 = fmaf(Ts[h * 4 + 1][k], w, a1);
      a2 = fmaf(Ts[h * 4 + 2][k], w, a2);
      a3 = fmaf(Ts[h * 4 + 3][k], w, a3);
    }
    float acc[4] = {a0, a1, a2, a3};
    float gvd = gld(gv2, d, f), bvd = gld(bv2, d, f);
#pragma unroll
    for (int rq = 0; rq < 4; ++rq) {
      int i = rq * 104 + g;
      float ssh = s_sh[((long)b * 6 + h) * 416 + i];
      float val = gvd * (acc[rq] - ssh) + bvd
                + c_buf[(((long)b * 6 + h) * 416 + i) * 128 + dh];
      opbf[((long)b * 416 + i) * 768 + d] = f2bf(val);
    }
  }
}

// ---------------------------------------------------------------- host ------
extern "C" void kernel_launch(void* const* d_in, const int* in_sizes, int n_in,
                              void* d_out, int out_size, void* d_ws, size_t ws_size,
                              hipStream_t stream)
{
  (void)in_sizes; (void)n_in;
  const void* x   = d_in[0];
  const void* ctx = d_in[1];
  const void* Wq  = d_in[2];
  const void* gq  = d_in[3];
  const void* bq  = d_in[4];
  const void* Wk  = d_in[5];
  const void* gk  = d_in[6];
  const void* bk  = d_in[7];
  const void* Wv  = d_in[8];
  const void* gv1 = d_in[9];
  const void* bv1 = d_in[10];
  const void* Wcv = d_in[11];
  const void* gv2 = d_in[12];
  const void* bv2 = d_in[13];
  const void* Wo  = d_in[14];
  const void* go  = d_in[15];
  const void* bo  = d_in[16];

  // -------- workspace layout --------
  const size_t SZ_FLAG = 256;
  const size_t SZ_QBF  = 2555904;
  const size_t SZ_KBF  = 1579008;
  const size_t SZ_MID  = 13684736;
  const size_t SZ_MM   = 1703936;
  const size_t SZ_WB   = 26624;
  const size_t SZ_MIDI = 14057472;   // 416 * 264 * 64 bf16 (264-row padded)
  const size_t SZ_PIM  = 427648;
  const size_t SZ_ABF  = 5271552;
  const size_t SZ_A2   = 5271552;
  const size_t SZ_SSH  = 39936;
  const size_t SZ_CB   = 1579008;
  const size_t SZ_WCVB = 10223616;   // 104*64*768 bf16
  const size_t SZ_YF   = 13684736;   // 104*1028*64 bf16
  const size_t SZ_WT   = 1179648;    // 768*768 bf16 (x3: WqT, WkT, WoT)
  const size_t SZ_WVT  = 10223616;   // 6656*768 bf16
  const size_t SZ_CTXT = 1622016;    // 4*768*264 bf16 (ctx^T, zero-padded cols)
  const size_t SZ_SIMF = 10263552;   // 24*416*257 fp32 (dedicated: Y reads midbf in same launch)
  const size_t REQUIRED = SZ_FLAG + SZ_QBF + SZ_KBF + SZ_MID + SZ_MM + SZ_WB +
                          SZ_MIDI + SZ_PIM + SZ_ABF + SZ_A2 + SZ_SSH + SZ_CB +
                          SZ_WCVB + SZ_YF + 3 * SZ_WT + SZ_WVT + SZ_CTXT + SZ_SIMF;  // 95,754,112

  if (ws_size < REQUIRED) {
    fill_k<<<(out_size + 255) / 256, 256, 0, stream>>>((u16*)d_out, (float)(ws_size >> 20), out_size);
    return;
  }

  char* p = (char*)d_ws;
  int*   dtf   = (int*)  p;                 p += SZ_FLAG;
  u16*   qbf   = (u16*)  p;                 p += SZ_QBF;
  u16*   kbf   = (u16*)  p;                 p += SZ_KBF;
  char*  midrg = p;                         p += SZ_MID;
  char*  mmrg  = p;                         p += SZ_MM;
  float* wbar  = (float*)p;                 p += SZ_WB;
  u16*   midi  = (u16*)  p;                 p += SZ_MIDI;
  float* pim   = (float*)p;                 p += SZ_PIM;
  char*  abfrg = p;                         p += SZ_ABF;
  u16*   A2bf  = (u16*)  p;                 p += SZ_A2;
  float* s_sh  = (float*)p;                 p += SZ_SSH;
  u16*   cb    = (u16*)  p;                 p += SZ_CB;
  u16*   wcvb  = (u16*)  p;                 p += SZ_WCVB;
  u16*   yfull = (u16*)  p;                 p += SZ_YF;
  u16*   wqt2  = (u16*)  p;                 p += SZ_WT;
  u16*   wkt2  = (u16*)  p;                 p += SZ_WT;
  u16*   wot2  = (u16*)  p;                 p += SZ_WT;
  u16*   wvt   = (u16*)  p;                 p += SZ_WVT;
  u16*   ctxT  = (u16*)  p;                 p += SZ_CTXT;
  float* simf  = (float*)p;                 p += SZ_SIMF;

  u16*   midbf = (u16*)midrg;
  float* c_buf = (float*)midrg;             // midbf dead after stats2
  u16*   Tb16  = (u16*)(midrg + 5111808);   // right after c_buf's 5,111,808 B
  u16*   Gb    = (u16*)mmrg;
  u16*   xb    = (u16*)abfrg;
  u16*   Abf   = (u16*)abfrg;
  u16*   opbf  = (u16*)abfrg;               // Abf dead after ct_k

  probe_k<<<1, 256, 0, stream>>>((const u32*)x, dtf);

  // prep: copies + midi pad zero (3597) | transposes (7584) | wbar (1664)
  prep_k<<<12845, 256, 0, stream>>>(x, xb, ctx, cb, Wcv, wcvb, midi,
                                    Wq, Wk, Wo, Wv, wqt2, wkt2, wot2, wvt, ctxT,
                                    wbar, dtf);

  // q/k/mid gemm128s (600) + Gram (104)
  mg4_k<<<704, 256, 0, stream>>>(xb, wqt2, qbf, cb, wkt2, kbf, wvt, midbf, wcvb, Gb);

  // q/k/mid LNs
  mln3_k<<<3720, 256, 0, stream>>>(qbf, gq, bq, kbf, gk, bk, midbf, gv1, bv1, dtf);

  // Y = mid_g @ M[g] (1768) + sim = scale^2 q@k^T (840)
  ysim_k<<<2608, 256, 0, stream>>>(midbf, Gb, yfull, qbf, kbf, simf);

  stats2_k<<<dim3(257, 104), 256, 0, stream>>>(midbf, yfull, wbar, midi, pim);
  softmax_k<<<dim3(24, 104), 256, 0, stream>>>(simf, pim, Abf, A2bf, s_sh);

  // c = A @ ctx_head (336) + T = A2 @ midi (416)
  ct_k<<<752, 256, 0, stream>>>(Abf, ctxT, c_buf, A2bf, midi, Tb16);

  // fused O-gemm + combine
  oc_k<<<416, 256, 0, stream>>>(Tb16, wcvb, s_sh, c_buf, gv2, bv2, opbf, dtf);

  // out = LN(out_pre @ Wo)
  {
    dim3 grid(13, 6, 1);
    gemm128<<<grid, dim3(256), 0, stream>>>(opbf, wot2, qbf, 1664, 768, 768, 768, 768, 768);
  }
  ln_rows<<<1664, 256, 0, stream>>>(qbf, go, bo, d_out, 768, dtf, 1);
}

// Round 6
// 262.949 us; speedup vs baseline: 1.5288x; 1.0391x over previous
//
#include <hip/hip_runtime.h>

// SubjBasisGenerator fused pipeline. B=4 NQ=416 NC=257 D=768 H=6 DH=128 G=104 R=4 LORA=64
// R16: R14 skeleton (cooperative mega-kernel R15 silently no-opped under the
//      harness's capture path -> all-zero output; reverted). Kept the one R15
//      change that needs no grid sync: stats2 fused into Y-gemm epilogue —
//      fp32 Y tile stays in LDS (As/Bs dead after K-loop), per-row reductions
//      write midi/pim directly. Removes stats2 dispatch + 27MB yfull traffic
//      (buffer deleted). 11 -> 10 dispatches.
// R14: dispatch 16->11 (prep/mg4/ysim/ct merges).
// R13/R12: merged q/k/mid gemm128s (B-panel-major), merged LNs/transposes,
//      ctx^T btrans fast path, K padded 257->264, 264-row-padded midi.
// R11: oc_k fusion (O-gemm+combine), Wconv bf16 pre-convert.
// R10: gemm128 — 128x128 tile, 4x4 MFMA acc/wave, global_load_lds width-16.
//
// Algebra: the grouped-conv+LN v-path decomposes exactly:
//   sum_j A_j v_j = gv2*( (sum_j A_j inv_j mid_j)@Wconv[g] - sum_j A_j inv_j mu_j )
//                   + bv2 + (A @ ctx)
//   q2[b,g,j] = mid^T M[g] mid = mid . (M[g] @ mid),  M[g] = Wconv[g]Wconv[g]^T/768

typedef unsigned short u16;
typedef unsigned int   u32;
typedef __attribute__((ext_vector_type(4))) float f32x4;
typedef __attribute__((ext_vector_type(4))) u32   u32x4;
typedef __attribute__((ext_vector_type(8))) short bf16x8;

__device__ __forceinline__ float bf2f(u16 v) { return __uint_as_float(((u32)v) << 16); }
__device__ __forceinline__ u16 f2bf(float f) {
  u32 u = __float_as_uint(f);
  u32 r = u + 0x7fffu + ((u >> 16) & 1u);  // RNE
  return (u16)(r >> 16);
}
__device__ __forceinline__ float gld(const void* p, long idx, int f32) {
  return f32 ? ((const float*)p)[idx] : bf2f(((const u16*)p)[idx]);
}

typedef const __attribute__((address_space(1))) u32 gas_u32;
typedef __attribute__((address_space(3))) u32 las_u32;

// async 16B/lane global->LDS; LDS dest = wave-uniform base + lane*16 (m97).
__device__ __forceinline__ void stage16(const u16* g, u16* lbase, int lane) {
#if __has_builtin(__builtin_amdgcn_global_load_lds)
  (void)lane;
  __builtin_amdgcn_global_load_lds((gas_u32*)g, (las_u32*)lbase, 16, 0, 0);
#else
  *(u32x4*)(lbase + lane * 8) = *(const u32x4*)g;
#endif
}

// ------------------------------------------------------------ dtype probe ---
__global__ __launch_bounds__(256) void probe_k(const u32* __restrict__ xw, int* __restrict__ flag) {
  int tid = threadIdx.x, c = 0;
  for (int i = tid; i < 4096; i += 256) {
    u16 lo = (u16)(xw[i] & 0xffffu);
    float a = fabsf(bf2f(lo));
    if (lo == 0 || (a >= 1e-3f && a <= 32.f)) ++c;
  }
#pragma unroll
  for (int o = 32; o; o >>= 1) c += __shfl_xor(c, o, 64);
  __shared__ int r[4];
  if ((tid & 63) == 0) r[tid >> 6] = c;
  __syncthreads();
  if (tid == 0) flag[0] = (r[0] + r[1] + r[2] + r[3] >= 2048) ? 0 : 1;  // 1 = fp32
}

// ------------------------------------------------------------ diag fill -----
__global__ __launch_bounds__(256) void fill_k(u16* p, float v, int n) {
  int i = blockIdx.x * 256 + threadIdx.x;
  if (i < n) p[i] = f2bf(v);
}

// --------------------------------------------------------------- prep_k -----
// blocks [0,3597): ext->bf16 copies (x, ctx, Wconv) + midi pad-row zeroing
// blocks [3597,11181): transposes Wq/Wk/Wo (768^2), Wv (768x6656), ctx^T
// blocks [11181,12845): wbar row means (reads RAW Wcv — no intra-launch dep)
__global__ __launch_bounds__(256) void prep_k(
    const void* __restrict__ x,   u16* __restrict__ xb,
    const void* __restrict__ ctx, u16* __restrict__ cbuf,
    const void* __restrict__ Wcv, u16* __restrict__ wcvb,
    u16* __restrict__ midi,
    const void* __restrict__ Wq, const void* __restrict__ Wk,
    const void* __restrict__ Wo, const void* __restrict__ Wv,
    u16* __restrict__ wqt, u16* __restrict__ wkt, u16* __restrict__ wot,
    u16* __restrict__ wvt, u16* __restrict__ ctxT,
    float* __restrict__ wbar, const int* __restrict__ dtf)
{
  const int f = dtf[0];
  int bid = blockIdx.x;
  __shared__ float s[32][33];
  if (bid < 3597) {
    // ---- convb4 ----
    const long n0_ = 1277952, n1_ = 789504, n2_ = 5111808, n3_ = 186368;
    long i = ((long)bid * 256 + threadIdx.x) * 8;
    const long t0 = n0_, t1 = t0 + n1_, t2 = t1 + n2_, t3 = t2 + n3_;
    if (i >= t3) return;
    if (i >= t2) {
      long e = i - t2;                 // zero 7 pad rows per midi z-block
      long z = e / 448, off = e - z * 448;
      u32x4 zz = {0u, 0u, 0u, 0u};
      *(u32x4*)(midi + z * 16896 + 16448 + off) = zz;
      return;
    }
    const void* in; u16* out;
    if (i < t0)      { in = x;    out = xb; }
    else if (i < t1) { in = ctx;  out = cbuf; i -= t0; }
    else             { in = Wcv;  out = wcvb; i -= t1; }
    if (f) {
      const float* ip = (const float*)in + i;
      f32x4 a = *(const f32x4*)ip, b = *(const f32x4*)(ip + 4);
      u32x4 q = { (u32)f2bf(a.x) | ((u32)f2bf(a.y) << 16),
                  (u32)f2bf(a.z) | ((u32)f2bf(a.w) << 16),
                  (u32)f2bf(b.x) | ((u32)f2bf(b.y) << 16),
                  (u32)f2bf(b.z) | ((u32)f2bf(b.w) << 16) };
      *(u32x4*)(out + i) = q;
    } else {
      *(u32x4*)(out + i) = *(const u32x4*)((const u16*)in + i);
    }
  } else if (bid < 11181) {
    // ---- transM ----
    int t = bid - 3597;
    const void* in; u16* out;
    int inK, inN, ldo, outK, nx;
    long inBase = 0, outBase = 0;
    if (t < 1728) {                    // 3 x 768x768 weights: 576 tiles each
      int w = t / 576; t -= w * 576;
      in  = w == 0 ? Wq : w == 1 ? Wk : Wo;
      out = w == 0 ? wqt : w == 1 ? wkt : wot;
      inK = 768; inN = 768; ldo = 768; outK = 768; nx = 24;
    } else if (t < 6720) {             // Wv 768x6656: 208 n-tiles x 24 k-tiles
      t -= 1728;
      in = Wv; out = wvt;
      inK = 768; inN = 6656; ldo = 768; outK = 768; nx = 208;
    } else {                           // ctxT: 4 b x (24 n-tiles x 9 k-tiles)
      t -= 6720;
      int b = t / 216; t -= b * 216;
      in = ctx; out = ctxT;
      inK = 257; inN = 768; ldo = 264; outK = 264; nx = 24;
      inBase = (long)b * 257 * 768; outBase = (long)b * 768 * 264;
    }
    int n0 = (t % nx) * 32, k0 = (t / nx) * 32;
    int tx = threadIdx.x & 31, ty = threadIdx.x >> 5;  // 32 x 8
#pragma unroll
    for (int i = 0; i < 32; i += 8) {
      int k = k0 + ty + i, n = n0 + tx;
      float v = 0.f;
      if (k < inK && n < inN) v = gld(in, inBase + (long)k * inN + n, f);
      s[ty + i][tx] = v;
    }
    __syncthreads();
#pragma unroll
    for (int i = 0; i < 32; i += 8) {
      int n = n0 + ty + i, k = k0 + tx;
      if (n < inN && k < outK) out[outBase + (long)n * ldo + k] = f2bf(s[tx][ty + i]);
    }
  } else {
    // ---- wbar: row means of raw Wconv, r = g*64+l over 768 cols ----
    int r = (bid - 11181) * 4 + (threadIdx.x >> 6);
    int lane = threadIdx.x & 63;
    long base = (long)r * 768;
    float sm = 0.f;
    for (int c = lane; c < 768; c += 64) sm += gld(Wcv, base + c, f);
#pragma unroll
    for (int o = 32; o; o >>= 1) sm += __shfl_xor(sm, o, 64);
    if (lane == 0) wbar[r] = sm * (1.f / 768.f);
  }
}

// ------------------------------------------------------------- gemm128 ------
// C_bf16 = A_bf16[M,K] @ B_bf16[N,K]^T. Requires N%128==0, K%32==0; M-tail via
// row-clamped staging + guarded writes. 128x128 tile, BK=32, 4 waves each 64x64.
__device__ __forceinline__ void gemm128_body(
    const u16* __restrict__ A, const u16* __restrict__ B, u16* __restrict__ C,
    int M, int N, int K, int lda, int ldb, int ldc, int m0, int n0)
{
  __shared__ __attribute__((aligned(16))) u16 As[128 * 32];
  __shared__ __attribute__((aligned(16))) u16 Bs[128 * 32];
  const int tid = threadIdx.x, lane = tid & 63, wave = tid >> 6;
  const int wm = (wave >> 1) * 64, wn = (wave & 1) * 64;
  const int fm = lane & 15, fq = lane >> 4;

  const int srow = lane >> 2, selem = (lane & 3) * 8;
  int ra1 = m0 + wave * 16 + srow;      if (ra1 > M - 1) ra1 = M - 1;
  int ra2 = m0 + 64 + wave * 16 + srow; if (ra2 > M - 1) ra2 = M - 1;
  const int rb1 = n0 + wave * 16 + srow;
  const int rb2 = n0 + 64 + wave * 16 + srow;
  const u16* pa1 = A + (long)ra1 * lda + selem;
  const u16* pa2 = A + (long)ra2 * lda + selem;
  const u16* pb1 = B + (long)rb1 * ldb + selem;
  const u16* pb2 = B + (long)rb2 * ldb + selem;
  u16* la1 = As + wave * 512;
  u16* la2 = As + 2048 + wave * 512;
  u16* lb1 = Bs + wave * 512;
  u16* lb2 = Bs + 2048 + wave * 512;

  f32x4 acc[4][4];
  const f32x4 zero4 = {0.f, 0.f, 0.f, 0.f};
#pragma unroll
  for (int a_ = 0; a_ < 4; ++a_)
#pragma unroll
    for (int b_ = 0; b_ < 4; ++b_) acc[a_][b_] = zero4;

  for (int k0 = 0; k0 < K; k0 += 32) {
    stage16(pa1, la1, lane);
    stage16(pa2, la2, lane);
    stage16(pb1, lb1, lane);
    stage16(pb2, lb2, lane);
    pa1 += 32; pa2 += 32; pb1 += 32; pb2 += 32;
    __syncthreads();
    bf16x8 fa[4], fb[4];
#pragma unroll
    for (int mt = 0; mt < 4; ++mt)
      fa[mt] = *(const bf16x8*)&As[(wm + mt * 16 + fm) * 32 + fq * 8];
#pragma unroll
    for (int nt = 0; nt < 4; ++nt)
      fb[nt] = *(const bf16x8*)&Bs[(wn + nt * 16 + fm) * 32 + fq * 8];
#pragma unroll
    for (int mt = 0; mt < 4; ++mt)
#pragma unroll
      for (int nt = 0; nt < 4; ++nt)
        acc[mt][nt] = __builtin_amdgcn_mfma_f32_16x16x32_bf16(fa[mt], fb[nt], acc[mt][nt], 0, 0, 0);
    __syncthreads();
  }
#pragma unroll
  for (int mt = 0; mt < 4; ++mt)
#pragma unroll
    for (int nt = 0; nt < 4; ++nt)
#pragma unroll
      for (int rr = 0; rr < 4; ++rr) {
        int gm = m0 + wm + mt * 16 + fq * 4 + rr;
        int gn = n0 + wn + nt * 16 + fm;
        if (gm < M) C[(long)gm * ldc + gn] = f2bf(acc[mt][nt][rr]);
      }
}

__global__ __launch_bounds__(256) void gemm128(
    const u16* __restrict__ A, const u16* __restrict__ B, u16* __restrict__ C,
    int M, int N, int K, int lda, int ldb, int ldc)
{
  gemm128_body(A, B, C, M, N, K, lda, ldb, ldc, blockIdx.x * 128, blockIdx.y * 128);
}

// ------------------------------------------------- gemm64 body (all-bf16) ---
// 64x64 tile, BK=32, 2x2 acc/wave. Pointers pre-offset by caller (batch z).
// If Ylds != nullptr: fp32 tile written to LDS (caller runs epilogue) instead
// of global. Ylds may alias As/Bs (dead after the K-loop's final barrier).
#define LDS_S 40

__device__ __forceinline__ void gemm64_body(
    u16* As, u16* Bs,
    const u16* __restrict__ A16, const u16* __restrict__ B16,
    float* Cf, u16* Cb, float* Ylds,
    int M, int N, int K, int lda, int ldb, int ldc,
    int btrans, float alpha, int m0, int n0)
{
  const int tid = threadIdx.x;
  const int lane = tid & 63, wave = tid >> 6;
  const int wm = (wave >> 1) * 32, wn = (wave & 1) * 32;
  const int fm = lane & 15, fq = lane >> 4;
  const int ar = tid >> 2, ak = (tid & 3) * 8;
  const int bk = tid >> 3, bn = (tid & 7) * 8;

  f32x4 acc[2][2];
  const f32x4 zero4 = {0.f, 0.f, 0.f, 0.f};
#pragma unroll
  for (int a_ = 0; a_ < 2; ++a_)
#pragma unroll
    for (int b_ = 0; b_ < 2; ++b_) acc[a_][b_] = zero4;

  for (int k0 = 0; k0 < K; k0 += 32) {
    {
      int gm = m0 + ar, gk = k0 + ak;
      long idx = (long)gm * lda + gk;
      if (gm < M && gk + 8 <= K) {
        *(u32x4*)&As[ar * LDS_S + ak] = *(const u32x4*)(A16 + idx);
      } else {
#pragma unroll
        for (int e = 0; e < 8; ++e)
          As[ar * LDS_S + ak + e] = (gm < M && gk + e < K) ? A16[idx + e] : (u16)0;
      }
    }
    if (btrans) {
      int gn = n0 + ar, gk = k0 + ak;
      long idx = (long)gn * ldb + gk;
      if (gn < N && gk + 8 <= K) {
        *(u32x4*)&Bs[ar * LDS_S + ak] = *(const u32x4*)(B16 + idx);
      } else {
#pragma unroll
        for (int e = 0; e < 8; ++e)
          Bs[ar * LDS_S + ak + e] = (gn < N && gk + e < K) ? B16[idx + e] : (u16)0;
      }
    } else {
      int gk = k0 + bk;
      long idx = (long)gk * ldb + n0 + bn;
      u16 tmp[8];
      if (gk < K) {
        u32x4 v = *(const u32x4*)(B16 + idx);
        tmp[0] = (u16)(v.x & 0xffff); tmp[1] = (u16)(v.x >> 16);
        tmp[2] = (u16)(v.y & 0xffff); tmp[3] = (u16)(v.y >> 16);
        tmp[4] = (u16)(v.z & 0xffff); tmp[5] = (u16)(v.z >> 16);
        tmp[6] = (u16)(v.w & 0xffff); tmp[7] = (u16)(v.w >> 16);
      } else {
#pragma unroll
        for (int e = 0; e < 8; ++e) tmp[e] = 0;
      }
      int rot = tid & 7;  // spread LDS bank writes
#pragma unroll
      for (int e = 0; e < 8; ++e) {
        int ee = (e + rot) & 7;
        Bs[(bn + ee) * LDS_S + bk] = tmp[ee];
      }
    }
    __syncthreads();
    {
      bf16x8 fa[2], fb[2];
      fa[0] = *(const bf16x8*)&As[(wm +      fm) * LDS_S + fq * 8];
      fa[1] = *(const bf16x8*)&As[(wm + 16 + fm) * LDS_S + fq * 8];
      fb[0] = *(const bf16x8*)&Bs[(wn +      fm) * LDS_S + fq * 8];
      fb[1] = *(const bf16x8*)&Bs[(wn + 16 + fm) * LDS_S + fq * 8];
#pragma unroll
      for (int mt = 0; mt < 2; ++mt)
#pragma unroll
        for (int nt = 0; nt < 2; ++nt)
          acc[mt][nt] = __builtin_amdgcn_mfma_f32_16x16x32_bf16(fa[mt], fb[nt], acc[mt][nt], 0, 0, 0);
    }
    __syncthreads();
  }
  if (Ylds) {
    // all LDS reads complete past the final barrier; safe to overwrite As/Bs
#pragma unroll
    for (int mt = 0; mt < 2; ++mt)
#pragma unroll
      for (int nt = 0; nt < 2; ++nt)
#pragma unroll
        for (int rr = 0; rr < 4; ++rr)
          Ylds[(wm + mt * 16 + fq * 4 + rr) * 64 + (wn + nt * 16 + fm)] = acc[mt][nt][rr];
  } else {
#pragma unroll
    for (int mt = 0; mt < 2; ++mt)
#pragma unroll
      for (int nt = 0; nt < 2; ++nt)
#pragma unroll
        for (int rr = 0; rr < 4; ++rr) {
          int gm = m0 + wm + mt * 16 + fq * 4 + rr;
          int gn = n0 + wn + nt * 16 + fm;
          if (gm < M && gn < N) {
            float v = alpha * acc[mt][nt][rr];
            if (Cb) Cb[(long)gm * ldc + gn] = f2bf(v);
            else    Cf[(long)gm * ldc + gn] = v;
          }
        }
  }
}

// -------------------------------------- mg4: q/k/mid gemm128s + Gram gemm ---
__global__ __launch_bounds__(256) void mg4_k(
    const u16* __restrict__ xb, const u16* __restrict__ wqt, u16* __restrict__ qbf,
    const u16* __restrict__ cbuf, const u16* __restrict__ wkt, u16* __restrict__ kbf,
    const u16* __restrict__ wvt, u16* __restrict__ midbf,
    const u16* __restrict__ wcvb, u16* __restrict__ Gb)
{
  int bid = blockIdx.x;
  if (bid < 600) {
    const u16 *A, *B; u16* C; int M, N, lid, mx;
    if (bid < 78)       { A = xb;   B = wqt; C = qbf;   M = 1664; N = 768;  lid = bid;       mx = 13; }
    else if (bid < 132) { A = cbuf; B = wkt; C = kbf;   M = 1028; N = 768;  lid = bid - 78;  mx = 9;  }
    else                { A = cbuf; B = wvt; C = midbf; M = 1028; N = 6656; lid = bid - 132; mx = 9;  }
    int m0 = (lid % mx) * 128, n0 = (lid / mx) * 128;
    gemm128_body(A, B, C, M, N, 768, 768, 768, N, m0, n0);
  } else {
    __shared__ __attribute__((aligned(16))) u16 As[64 * LDS_S];
    __shared__ __attribute__((aligned(16))) u16 Bs[64 * LDS_S];
    int z = bid - 600;   // 0..103: M[g] = Wconv_b[g] @ Wconv_b[g]^T / 768
    gemm64_body(As, Bs, wcvb + (long)z * 49152, wcvb + (long)z * 49152,
                nullptr, Gb + (long)z * 4096, nullptr,
                64, 64, 768, 768, 768, 64, 1, 1.f / 768.f, 0, 0);
  }
}

// --------------------- ysim: Y-gemm with fused stats epilogue + sim-gemm ----
__global__ __launch_bounds__(256) void ysim_k(
    const u16* __restrict__ midbf, const u16* __restrict__ Gb,
    const float* __restrict__ wbar, u16* __restrict__ midi, float* __restrict__ pim,
    const u16* __restrict__ qbf, const u16* __restrict__ kbf, float* __restrict__ simf)
{
  __shared__ __attribute__((aligned(16))) char smem[16384];
  u16* As = (u16*)smem;
  u16* Bs = (u16*)(smem + 8192);
  int bid = blockIdx.x;
  if (bid < 1768) {
    // Y = mid_g[1028x64] @ M[g]^T -> fp32 tile in LDS, then stats epilogue
    int g = bid / 17, bx = bid % 17;
    int m0 = bx * 64;
    float* Ylds = (float*)smem;   // aliases As/Bs (dead after final barrier)
    gemm64_body(As, Bs, midbf + (long)g * 64, Gb + (long)g * 4096,
                nullptr, nullptr, Ylds,
                1028, 64, 64, 6656, 64, 64, 1, 1.f, m0, 0);
    __syncthreads();
    int tid = threadIdx.x, lane = tid & 63, wave = tid >> 6;
#pragma unroll
    for (int rr = 0; rr < 16; ++rr) {
      int r = wave * 16 + rr;          // local row
      int gr = m0 + r;                 // global row (wave-uniform)
      if (gr < 1028) {
        float m  = bf2f(midbf[(long)gr * 6656 + g * 64 + lane]);
        float y  = Ylds[r * 64 + lane];
        float wb = wbar[g * 64 + lane];
        float mup = m * wb, q2p = m * y;
#pragma unroll
        for (int o = 32; o; o >>= 1) { mup += __shfl_xor(mup, o, 64); q2p += __shfl_xor(q2p, o, 64); }
        float var = q2p - mup * mup;
        float inv = rsqrtf(fmaxf(var, 0.f) + 1e-5f);
        int b = gr / 257, j = gr - b * 257;
        long zidx = (long)b * 104 + g;
        midi[(zidx * 264 + j) * 64 + lane] = f2bf(inv * m);
        if (lane == 0) pim[zidx * 257 + j] = inv * mup;
      }
    }
  } else {
    // sim = scale^2 * q @ k^T;  z = b*6+h
    int lid = bid - 1768; int z = lid / 35, r = lid % 35, bx = r % 7, by = r / 7;
    const u16* A = qbf + (long)(z / 6) * 319488 + (long)(z % 6) * 128;
    const u16* B = kbf + (long)(z / 6) * 197376 + (long)(z % 6) * 128;
    float* Cf = simf + (long)z * 106912;
    gemm64_body(As, Bs, A, B, Cf, nullptr, nullptr,
                416, 257, 128, 768, 768, 257, 1, 0.08838834764831845f, bx * 64, by * 64);
  }
}

// --------------------------------------------------- ct: c-gemm + T-gemm ----
__global__ __launch_bounds__(256) void ct_k(
    const u16* __restrict__ Abf, const u16* __restrict__ ctxT, float* __restrict__ c_buf,
    const u16* __restrict__ A2bf, const u16* __restrict__ midi, u16* __restrict__ Tb16)
{
  __shared__ __attribute__((aligned(16))) u16 As[64 * LDS_S];
  __shared__ __attribute__((aligned(16))) u16 Bs[64 * LDS_S];
  int bid = blockIdx.x;
  if (bid < 336) {
    // c = A @ ctx_head (btrans via ctx^T, K=264); z = b*6+h
    int z = bid / 14, r = bid % 14, bx = r % 7, by = r / 7;
    const u16* A = Abf + (long)z * 109824;
    const u16* B = ctxT + (long)(z / 6) * 202752 + (long)(z % 6) * 33792;
    float* Cf = c_buf + (long)z * 53248;
    gemm64_body(As, Bs, A, B, Cf, nullptr, nullptr,
                416, 128, 264, 264, 264, 128, 1, 1.f, bx * 64, by * 64);
  } else {
    // T = A2 @ midi (non-trans, K=264, 264-row-padded midi); z = b*104+g
    int z = bid - 336;
    const u16* A = A2bf + (long)z * 6336;
    const u16* B = midi + (long)z * 16896;
    u16* Cb = Tb16 + (long)z * 1536;
    gemm64_body(As, Bs, A, B, nullptr, Cb, nullptr,
                24, 64, 264, 264, 64, 64, 0, 1.f, 0, 0);
  }
}

// ------------------------------------------------------------- row LN -------
__device__ __forceinline__ void ln_row(
    const u16* __restrict__ ip, const void* __restrict__ g, const void* __restrict__ b,
    u16* __restrict__ ob, float* __restrict__ of, int N, int f)
{
  int tid = threadIdx.x, lane = tid & 63, wave = tid >> 6;
  const int nv = N >> 3;
  float s1 = 0.f, s2 = 0.f;
  for (int c8 = tid; c8 < nv; c8 += 256) {
    u32x4 v = *(const u32x4*)(ip + c8 * 8);
    float e0 = bf2f((u16)(v.x & 0xffff)), e1 = bf2f((u16)(v.x >> 16));
    float e2 = bf2f((u16)(v.y & 0xffff)), e3 = bf2f((u16)(v.y >> 16));
    float e4 = bf2f((u16)(v.z & 0xffff)), e5 = bf2f((u16)(v.z >> 16));
    float e6 = bf2f((u16)(v.w & 0xffff)), e7 = bf2f((u16)(v.w >> 16));
    s1 += ((e0 + e1) + (e2 + e3)) + ((e4 + e5) + (e6 + e7));
    s2 += ((e0*e0 + e1*e1) + (e2*e2 + e3*e3)) + ((e4*e4 + e5*e5) + (e6*e6 + e7*e7));
  }
#pragma unroll
  for (int o = 32; o; o >>= 1) { s1 += __shfl_xor(s1, o, 64); s2 += __shfl_xor(s2, o, 64); }
  __shared__ float red[8];
  if (lane == 0) { red[wave] = s1; red[4 + wave] = s2; }
  __syncthreads();
  s1 = red[0] + red[1] + red[2] + red[3];
  s2 = red[4] + red[5] + red[6] + red[7];
  float mean = s1 / N;
  float var = s2 / N - mean * mean;
  float rstd = rsqrtf(fmaxf(var, 0.f) + 1e-5f);
  for (int c8 = tid; c8 < nv; c8 += 256) {
    int c = c8 * 8;
    u32x4 v = *(const u32x4*)(ip + c);
    float e[8];
    e[0] = bf2f((u16)(v.x & 0xffff)); e[1] = bf2f((u16)(v.x >> 16));
    e[2] = bf2f((u16)(v.y & 0xffff)); e[3] = bf2f((u16)(v.y >> 16));
    e[4] = bf2f((u16)(v.z & 0xffff)); e[5] = bf2f((u16)(v.z >> 16));
    e[6] = bf2f((u16)(v.w & 0xffff)); e[7] = bf2f((u16)(v.w >> 16));
    float gg[8], bb[8];
    if (f) {
      const float* gp = (const float*)g + c; const float* bp = (const float*)b + c;
      f32x4 g0 = *(const f32x4*)gp, g1 = *(const f32x4*)(gp + 4);
      f32x4 b0 = *(const f32x4*)bp, b1 = *(const f32x4*)(bp + 4);
      gg[0]=g0.x; gg[1]=g0.y; gg[2]=g0.z; gg[3]=g0.w; gg[4]=g1.x; gg[5]=g1.y; gg[6]=g1.z; gg[7]=g1.w;
      bb[0]=b0.x; bb[1]=b0.y; bb[2]=b0.z; bb[3]=b0.w; bb[4]=b1.x; bb[5]=b1.y; bb[6]=b1.z; bb[7]=b1.w;
    } else {
      u32x4 gv = *(const u32x4*)((const u16*)g + c);
      u32x4 bv = *(const u32x4*)((const u16*)b + c);
      gg[0]=bf2f((u16)(gv.x&0xffff)); gg[1]=bf2f((u16)(gv.x>>16));
      gg[2]=bf2f((u16)(gv.y&0xffff)); gg[3]=bf2f((u16)(gv.y>>16));
      gg[4]=bf2f((u16)(gv.z&0xffff)); gg[5]=bf2f((u16)(gv.z>>16));
      gg[6]=bf2f((u16)(gv.w&0xffff)); gg[7]=bf2f((u16)(gv.w>>16));
      bb[0]=bf2f((u16)(bv.x&0xffff)); bb[1]=bf2f((u16)(bv.x>>16));
      bb[2]=bf2f((u16)(bv.y&0xffff)); bb[3]=bf2f((u16)(bv.y>>16));
      bb[4]=bf2f((u16)(bv.z&0xffff)); bb[5]=bf2f((u16)(bv.z>>16));
      bb[6]=bf2f((u16)(bv.w&0xffff)); bb[7]=bf2f((u16)(bv.w>>16));
    }
    float o_[8];
#pragma unroll
    for (int e2i = 0; e2i < 8; ++e2i) o_[e2i] = (e[e2i] - mean) * rstd * gg[e2i] + bb[e2i];
    if (of) {
      f32x4 o0 = {o_[0], o_[1], o_[2], o_[3]}, o1 = {o_[4], o_[5], o_[6], o_[7]};
      *(f32x4*)(of + c) = o0; *(f32x4*)(of + c + 4) = o1;
    } else {
      u32x4 q = { (u32)f2bf(o_[0]) | ((u32)f2bf(o_[1]) << 16),
                  (u32)f2bf(o_[2]) | ((u32)f2bf(o_[3]) << 16),
                  (u32)f2bf(o_[4]) | ((u32)f2bf(o_[5]) << 16),
                  (u32)f2bf(o_[6]) | ((u32)f2bf(o_[7]) << 16) };
      *(u32x4*)(ob + c) = q;
    }
  }
}

__global__ __launch_bounds__(256) void ln_rows(
    const u16* __restrict__ in, const void* __restrict__ g, const void* __restrict__ b,
    void* __restrict__ out, int N, const int* __restrict__ dtf, int isfinal)
{
  const int f = dtf[0];
  long row = blockIdx.x;
  const u16* ip = in + row * N;
  float* of = (isfinal && f) ? (float*)out + row * N : nullptr;
  u16*   ob = of ? nullptr : (u16*)out + row * N;
  ln_row(ip, g, b, ob, of, N, f);
}

// merged LN for q (1664x768), k (1028x768), mid (1028x6656)
__global__ __launch_bounds__(256) void mln3_k(
    u16* __restrict__ qb, const void* __restrict__ gq, const void* __restrict__ bq,
    u16* __restrict__ kb, const void* __restrict__ gk, const void* __restrict__ bk,
    u16* __restrict__ mb, const void* __restrict__ gv, const void* __restrict__ bv,
    const int* __restrict__ dtf)
{
  const int f = dtf[0];
  int row = blockIdx.x;
  u16* ip; const void *g, *b; int N;
  if (row < 1664)      { ip = qb + (long)row * 768; g = gq; b = bq; N = 768; }
  else if (row < 2692) { ip = kb + (long)(row - 1664) * 768; g = gk; b = bk; N = 768; }
  else                 { ip = mb + (long)(row - 2692) * 6656; g = gv; b = bv; N = 6656; }
  ln_row(ip, g, b, ip, nullptr, N, f);
}

// ------------------------------------------------------------- softmax ------
__global__ __launch_bounds__(256) void softmax_k(
    const float* __restrict__ simf, const float* __restrict__ pim,
    u16* __restrict__ Abf, u16* __restrict__ A2bf, float* __restrict__ s_sh)
{
  int bh = blockIdx.x;
  int b = bh / 6, h = bh - b * 6;
  int tid = threadIdx.x, lane = tid & 63, wave = tid >> 6;
  int i = blockIdx.y * 4 + wave;
  int g = i % 104, rq = i / 104;
  const float* sp_ = simf + ((long)bh * 416 + i) * 257;
  float s[5];
#pragma unroll
  for (int jc = 0; jc < 5; ++jc) {
    int j = jc * 64 + lane;
    s[jc] = (j < 257) ? sp_[j] : -1e30f;
  }
  float mx = -1e30f;
#pragma unroll
  for (int jc = 0; jc < 5; ++jc) mx = fmaxf(mx, s[jc]);
#pragma unroll
  for (int o = 32; o; o >>= 1) mx = fmaxf(mx, __shfl_xor(mx, o, 64));
  float p[5], sum = 0.f, sp = 0.f;
  long pimb = ((long)b * 104 + g) * 257;
#pragma unroll
  for (int jc = 0; jc < 5; ++jc) {
    int j = jc * 64 + lane;
    float pv = 0.f;
    if (j < 257) { pv = __expf(s[jc] - mx); sp = fmaf(pv, pim[pimb + j], sp); }
    p[jc] = pv; sum += pv;
  }
#pragma unroll
  for (int o = 32; o; o >>= 1) { sum += __shfl_xor(sum, o, 64); sp += __shfl_xor(sp, o, 64); }
  float rs = 1.f / sum;
  long arow  = ((long)bh * 416 + i) * 264;
  long a2row = (((long)b * 104 + g) * 24 + h * 4 + rq) * 264;
#pragma unroll
  for (int jc = 0; jc < 5; ++jc) {
    int j = jc * 64 + lane;
    if (j < 257) { u16 pb = f2bf(p[jc] * rs); Abf[arow + j] = pb; A2bf[a2row + j] = pb; }
    else if (j < 264) { Abf[arow + j] = 0; A2bf[a2row + j] = 0; }
  }
  if (lane == 0) s_sh[(long)bh * 416 + i] = sp * rs;
}

// -------------------------------------------------- fused O-gemm + combine --
__global__ __launch_bounds__(256) void oc_k(
    const u16* __restrict__ T, const u16* __restrict__ Wb,
    const float* __restrict__ s_sh, const float* __restrict__ c_buf,
    const void* __restrict__ gv2, const void* __restrict__ bv2,
    u16* __restrict__ opbf, const int* __restrict__ dtf)
{
  const int f = dtf[0];
  int z = blockIdx.x;                 // b*104+g
  int b = z / 104, g = z - b * 104;
  int tid = threadIdx.x;
  __shared__ float Ts[24][64];        // 6 KB
  const u16* tp = T + (long)z * 1536;
  for (int idx = tid; idx < 1536; idx += 256) Ts[idx >> 6][idx & 63] = bf2f(tp[idx]);
  __syncthreads();
  const int dh = tid & 127;
  const int hbase = (tid >> 7) * 3;   // threads 0..127 -> h 0..2, 128..255 -> h 3..5
  const u16* wg = Wb + (long)g * 49152;
#pragma unroll
  for (int hh = 0; hh < 3; ++hh) {
    int h = hbase + hh;
    int d = h * 128 + dh;
    const u16* wp = wg + d;
    float a0 = 0.f, a1 = 0.f, a2 = 0.f, a3 = 0.f;
#pragma unroll 16
    for (int k = 0; k < 64; ++k) {
      float w = bf2f(wp[(long)k * 768]);
      a0 = fmaf(Ts[h * 4 + 0][k], w, a0);
      a1 = fmaf(Ts[h * 4 + 1][k], w, a1);
      a2 = fmaf(Ts[h * 4 + 2][k], w, a2);
      a3 = fmaf(Ts[h * 4 + 3][k], w, a3);
    }
    float acc[4] = {a0, a1, a2, a3};
    float gvd = gld(gv2, d, f), bvd = gld(bv2, d, f);
#pragma unroll
    for (int rq = 0; rq < 4; ++rq) {
      int i = rq * 104 + g;
      float ssh = s_sh[((long)b * 6 + h) * 416 + i];
      float val = gvd * (acc[rq] - ssh) + bvd
                + c_buf[(((long)b * 6 + h) * 416 + i) * 128 + dh];
      opbf[((long)b * 416 + i) * 768 + d] = f2bf(val);
    }
  }
}

// ---------------------------------------------------------------- host ------
extern "C" void kernel_launch(void* const* d_in, const int* in_sizes, int n_in,
                              void* d_out, int out_size, void* d_ws, size_t ws_size,
                              hipStream_t stream)
{
  (void)in_sizes; (void)n_in;
  const void* x   = d_in[0];
  const void* ctx = d_in[1];
  const void* Wq  = d_in[2];
  const void* gq  = d_in[3];
  const void* bq  = d_in[4];
  const void* Wk  = d_in[5];
  const void* gk  = d_in[6];
  const void* bk  = d_in[7];
  const void* Wv  = d_in[8];
  const void* gv1 = d_in[9];
  const void* bv1 = d_in[10];
  const void* Wcv = d_in[11];
  const void* gv2 = d_in[12];
  const void* bv2 = d_in[13];
  const void* Wo  = d_in[14];
  const void* go  = d_in[15];
  const void* bo  = d_in[16];

  // -------- workspace layout --------
  const size_t SZ_FLAG = 256;
  const size_t SZ_QBF  = 2555904;
  const size_t SZ_KBF  = 1579008;
  const size_t SZ_MID  = 13684736;
  const size_t SZ_MM   = 1703936;
  const size_t SZ_WB   = 26624;
  const size_t SZ_MIDI = 14057472;   // 416 * 264 * 64 bf16 (264-row padded)
  const size_t SZ_PIM  = 427648;
  const size_t SZ_ABF  = 5271552;
  const size_t SZ_A2   = 5271552;
  const size_t SZ_SSH  = 39936;
  const size_t SZ_CB   = 1579008;
  const size_t SZ_WCVB = 10223616;   // 104*64*768 bf16
  const size_t SZ_WT   = 1179648;    // 768*768 bf16 (x3: WqT, WkT, WoT)
  const size_t SZ_WVT  = 10223616;   // 6656*768 bf16
  const size_t SZ_CTXT = 1622016;    // 4*768*264 bf16 (ctx^T, zero-padded cols)
  const size_t SZ_SIMF = 10263552;   // 24*416*257 fp32 (dedicated)
  const size_t REQUIRED = SZ_FLAG + SZ_QBF + SZ_KBF + SZ_MID + SZ_MM + SZ_WB +
                          SZ_MIDI + SZ_PIM + SZ_ABF + SZ_A2 + SZ_SSH + SZ_CB +
                          SZ_WCVB + 3 * SZ_WT + SZ_WVT + SZ_CTXT + SZ_SIMF;  // 82,069,376

  if (ws_size < REQUIRED) {
    fill_k<<<(out_size + 255) / 256, 256, 0, stream>>>((u16*)d_out, (float)(ws_size >> 20), out_size);
    return;
  }

  char* p = (char*)d_ws;
  int*   dtf   = (int*)  p;                 p += SZ_FLAG;
  u16*   qbf   = (u16*)  p;                 p += SZ_QBF;
  u16*   kbf   = (u16*)  p;                 p += SZ_KBF;
  char*  midrg = p;                         p += SZ_MID;
  char*  mmrg  = p;                         p += SZ_MM;
  float* wbar  = (float*)p;                 p += SZ_WB;
  u16*   midi  = (u16*)  p;                 p += SZ_MIDI;
  float* pim   = (float*)p;                 p += SZ_PIM;
  char*  abfrg = p;                         p += SZ_ABF;
  u16*   A2bf  = (u16*)  p;                 p += SZ_A2;
  float* s_sh  = (float*)p;                 p += SZ_SSH;
  u16*   cb    = (u16*)  p;                 p += SZ_CB;
  u16*   wcvb  = (u16*)  p;                 p += SZ_WCVB;
  u16*   wqt2  = (u16*)  p;                 p += SZ_WT;
  u16*   wkt2  = (u16*)  p;                 p += SZ_WT;
  u16*   wot2  = (u16*)  p;                 p += SZ_WT;
  u16*   wvt   = (u16*)  p;                 p += SZ_WVT;
  u16*   ctxT  = (u16*)  p;                 p += SZ_CTXT;
  float* simf  = (float*)p;                 p += SZ_SIMF;

  u16*   midbf = (u16*)midrg;
  float* c_buf = (float*)midrg;             // midbf dead after ysim stats
  u16*   Tb16  = (u16*)(midrg + 5111808);   // right after c_buf's 5,111,808 B
  u16*   Gb    = (u16*)mmrg;
  u16*   xb    = (u16*)abfrg;
  u16*   Abf   = (u16*)abfrg;
  u16*   opbf  = (u16*)abfrg;               // Abf dead after ct_k

  probe_k<<<1, 256, 0, stream>>>((const u32*)x, dtf);

  // prep: copies + midi pad zero (3597) | transposes (7584) | wbar (1664)
  prep_k<<<12845, 256, 0, stream>>>(x, xb, ctx, cb, Wcv, wcvb, midi,
                                    Wq, Wk, Wo, Wv, wqt2, wkt2, wot2, wvt, ctxT,
                                    wbar, dtf);

  // q/k/mid gemm128s (600) + Gram (104)
  mg4_k<<<704, 256, 0, stream>>>(xb, wqt2, qbf, cb, wkt2, kbf, wvt, midbf, wcvb, Gb);

  // q/k/mid LNs
  mln3_k<<<3720, 256, 0, stream>>>(qbf, gq, bq, kbf, gk, bk, midbf, gv1, bv1, dtf);

  // Y = mid_g @ M[g] with fused stats epilogue (1768) + sim (840)
  ysim_k<<<2608, 256, 0, stream>>>(midbf, Gb, wbar, midi, pim, qbf, kbf, simf);

  softmax_k<<<dim3(24, 104), 256, 0, stream>>>(simf, pim, Abf, A2bf, s_sh);

  // c = A @ ctx_head (336) + T = A2 @ midi (416)
  ct_k<<<752, 256, 0, stream>>>(Abf, ctxT, c_buf, A2bf, midi, Tb16);

  // fused O-gemm + combine
  oc_k<<<416, 256, 0, stream>>>(Tb16, wcvb, s_sh, c_buf, gv2, bv2, opbf, dtf);

  // out = LN(out_pre @ Wo)
  {
    dim3 grid(13, 6, 1);
    gemm128<<<grid, dim3(256), 0, stream>>>(opbf, wot2, qbf, 1664, 768, 768, 768, 768, 768);
  }
  ln_rows<<<1664, 256, 0, stream>>>(qbf, go, bo, d_out, 768, dtf, 1);
}